// Round 1
// 600.073 us; speedup vs baseline: 1.0007x; 1.0007x over previous
//
#include <hip/hip_runtime.h>

typedef unsigned short u16;
typedef __attribute__((ext_vector_type(8))) short bf16x8;
typedef __attribute__((ext_vector_type(16))) float f32x16;

__device__ __forceinline__ unsigned f2bf(float f) {
  unsigned u = __float_as_uint(f);
  return (u + 0x7fffu + ((u >> 16) & 1u)) >> 16;  // RNE fp32 -> bf16 bits
}

// async global->LDS, 16B per lane. LDS dest is wave-uniform base + lane*16.
__device__ __forceinline__ void async16(const u16* g, u16* l) {
  __builtin_amdgcn_global_load_lds(
      (const __attribute__((address_space(1))) void*)g,
      (__attribute__((address_space(3))) void*)l, 16, 0, 0);
}

// ---------------------------------------------------------------------------
// Pipelined MFMA GEMM: C[bz](M x 256-slice) = A[bz] @ B[bz]^T
//   A: m-major k-contiguous bf16 (lda), B: n-major k-contiguous bf16 (ldb).
//   BM=128, BN=256, BK=64, 512 thr (8 waves, 2Mx4N, each 64m x 64n),
//   mfma_32x32x16. A and B BOTH double-buffered (96 KB LDS, 1 block/CU);
//   counted s_waitcnt vmcnt(6) keeps the full next-tile prefetch in flight
//   across the whole compute phase (no mid-loop drain). XOR chunk swizzle
//   (phys = log ^ (row&7)) folded into the global fetch.
//   XCD batch clustering: fid%8 == XCD (round-robin dispatch); each XCD gets
//   2 whole batches -> per-XCD B panel working set 2 MB, L2-resident.
// EPI: 0 = plain bf16 store; 1 = +bias,LN(256),ReLU -> bf16 store;
//      2 = +bias,LN(256),ReLU -> column sums atomicAdd into gcn.
// ---------------------------------------------------------------------------
template<int EPI>
__global__ __launch_bounds__(512, 2) void mm128(
    const u16* __restrict__ Aop, const u16* __restrict__ Bop,
    int K, int lda, int ldb, int ldc,
    long long sA, long long sB, long long sC,
    const float* __restrict__ bias, const float* __restrict__ gam,
    const float* __restrict__ bet, u16* __restrict__ Cb, float* __restrict__ gcn)
{
  __shared__ __align__(16) u16 As[2][128 * 64];   // 2 x 16 KB
  __shared__ __align__(16) u16 Bs[2][256 * 64];   // 2 x 32 KB
  const int tid = threadIdx.x;
  const int w = tid >> 6, lane = tid & 63, l31 = lane & 31, half = lane >> 5;
  const int wm = w >> 2, wn = w & 3;              // wave tile: 64m x 64n

  // XCD batch clustering (grid is always 16 batches, pb blocks per batch)
  const int fid = blockIdx.x + gridDim.x * (blockIdx.y + gridDim.y * blockIdx.z);
  const int pb = gridDim.x * gridDim.y;
  int idx = fid >> 3;
  int bz = fid & 7;
  if (idx >= pb) { bz += 8; idx -= pb; }
  const int m0 = (int)(idx % gridDim.x) * 128;
  const int n0 = (int)(idx / gridDim.x) * 256;

  // staging map: each call covers 64 rows; thread -> (row tid>>3, phys chunk tid&7),
  // logical chunk = phys ^ (row&7)  (row offsets are multiples of 64 so row&7 = srow&7)
  const int srow = tid >> 3;
  const int clog = (tid & 7) ^ (srow & 7);
  const u16* Ag = Aop + sA * bz + (size_t)(m0 + srow) * lda + clog * 8;
  const u16* Bg = Bop + sB * bz + (size_t)(n0 + srow) * ldb + clog * 8;

  f32x16 acc[2][2];
#pragma unroll
  for (int i = 0; i < 2; i++)
#pragma unroll
    for (int j = 0; j < 2; j++)
#pragma unroll
      for (int r = 0; r < 16; r++) acc[i][j][r] = 0.f;

  const int niter = K >> 6;
  // prologue: tile 0 into buf 0 (6 loads/thread)
  {
    u16* Ad = As[0]; u16* Bd = Bs[0];
    async16(Ag, Ad + tid * 8);
    async16(Ag + (size_t)64 * lda, Ad + 4096 + tid * 8);
#pragma unroll
    for (int p = 0; p < 4; p++)
      async16(Bg + (size_t)(p * 64) * ldb, Bd + p * 4096 + tid * 8);
  }

  for (int i = 0; i < niter; i++) {
    if (i + 1 < niter) {                     // prefetch tile i+1, stays in flight
      const int k1 = (i + 1) << 6;
      u16* Ad = As[(i + 1) & 1]; u16* Bd = Bs[(i + 1) & 1];
      async16(Ag + k1, Ad + tid * 8);
      async16(Ag + (size_t)64 * lda + k1, Ad + 4096 + tid * 8);
#pragma unroll
      for (int p = 0; p < 4; p++)
        async16(Bg + (size_t)(p * 64) * ldb + k1, Bd + p * 4096 + tid * 8);
      __builtin_amdgcn_s_waitcnt(0x0F76);    // vmcnt(6): drain tile i, keep i+1
    } else {
      __builtin_amdgcn_s_waitcnt(0x0F70);    // vmcnt(0)
    }
    __builtin_amdgcn_s_barrier();            // tile i visible to all waves
    __asm__ volatile("" ::: "memory");
    const u16* Ab = As[i & 1];
    const u16* Bb = Bs[i & 1];
#pragma unroll
    for (int kk = 0; kk < 4; kk++) {
      const int pc = ((kk * 2 + half) ^ (l31 & 7)) * 8;
      const bf16x8 a0 = *(const bf16x8*)(Ab + (wm * 64 + l31) * 64 + pc);
      const bf16x8 a1 = *(const bf16x8*)(Ab + (wm * 64 + 32 + l31) * 64 + pc);
      const bf16x8 b0 = *(const bf16x8*)(Bb + (wn * 64 + l31) * 64 + pc);
      const bf16x8 b1 = *(const bf16x8*)(Bb + (wn * 64 + 32 + l31) * 64 + pc);
      acc[0][0] = __builtin_amdgcn_mfma_f32_32x32x16_bf16(a0, b0, acc[0][0], 0, 0, 0);
      acc[0][1] = __builtin_amdgcn_mfma_f32_32x32x16_bf16(a0, b1, acc[0][1], 0, 0, 0);
      acc[1][0] = __builtin_amdgcn_mfma_f32_32x32x16_bf16(a1, b0, acc[1][0], 0, 0, 0);
      acc[1][1] = __builtin_amdgcn_mfma_f32_32x32x16_bf16(a1, b1, acc[1][1], 0, 0, 0);
    }
    __asm__ volatile("" ::: "memory");
    __builtin_amdgcn_s_barrier();            // readers done before next overwrite
  }

  // C/D layout: col = wn*64 + nt*32 + l31; row_local = wm*64 + mt*32 + (r&3)+8*(r>>2)+4*half
  const int col0 = wn * 64 + l31;

  if constexpr (EPI == 0) {
#pragma unroll
    for (int mt = 0; mt < 2; mt++)
#pragma unroll
      for (int r = 0; r < 16; r++) {
        const int rl = (r & 3) + 8 * (r >> 2) + 4 * half;
        const long long row = (long long)m0 + wm * 64 + mt * 32 + rl;
        Cb[sC * bz + row * ldc + n0 + col0]      = (u16)f2bf(acc[mt][0][r]);
        Cb[sC * bz + row * ldc + n0 + col0 + 32] = (u16)f2bf(acc[mt][1][r]);
      }
    return;
  }

  // ---- LN epilogue (EPI 1/2): +bias, LN over 256 cols per row, ReLU ----
  __syncthreads();                           // full drain before As reuse as scratch
  const float bia0 = bias[col0], bia1 = bias[col0 + 32];
  float s2[2][16];
#pragma unroll
  for (int mt = 0; mt < 2; mt++)
#pragma unroll
    for (int r = 0; r < 16; r++) {
      acc[mt][0][r] += bia0;
      acc[mt][1][r] += bia1;
      s2[mt][r] = acc[mt][0][r] + acc[mt][1][r];
    }
#pragma unroll
  for (int off = 1; off <= 16; off <<= 1)
#pragma unroll
    for (int mt = 0; mt < 2; mt++)
#pragma unroll
      for (int r = 0; r < 16; r++) s2[mt][r] += __shfl_xor(s2[mt][r], off);

  // scratch in As (8192 floats): rowp[4][128] @0, mu[128] @512, iv[128] @640
  float* sm = (float*)As;
  if (l31 == 0) {
#pragma unroll
    for (int mt = 0; mt < 2; mt++)
#pragma unroll
      for (int r = 0; r < 16; r++) {
        const int rl = (r & 3) + 8 * (r >> 2) + 4 * half;
        sm[wn * 128 + wm * 64 + mt * 32 + rl] = s2[mt][r];
      }
  }
  __syncthreads();
  if (tid < 128)
    sm[512 + tid] = (sm[tid] + sm[128 + tid] + sm[256 + tid] + sm[384 + tid]) * (1.f / 256.f);
  __syncthreads();
  float4 mu4[2][4];
#pragma unroll
  for (int mt = 0; mt < 2; mt++)
#pragma unroll
    for (int g = 0; g < 4; g++)
      mu4[mt][g] = *(const float4*)(sm + 512 + wm * 64 + mt * 32 + g * 8 + 4 * half);

  float q2[2][16];
#pragma unroll
  for (int mt = 0; mt < 2; mt++)
#pragma unroll
    for (int r = 0; r < 16; r++) {
      const float mu = ((const float*)&mu4[mt][r >> 2])[r & 3];
      const float d0 = acc[mt][0][r] - mu, d1 = acc[mt][1][r] - mu;
      q2[mt][r] = d0 * d0 + d1 * d1;
    }
#pragma unroll
  for (int off = 1; off <= 16; off <<= 1)
#pragma unroll
    for (int mt = 0; mt < 2; mt++)
#pragma unroll
      for (int r = 0; r < 16; r++) q2[mt][r] += __shfl_xor(q2[mt][r], off);
  __syncthreads();
  if (l31 == 0) {
#pragma unroll
    for (int mt = 0; mt < 2; mt++)
#pragma unroll
      for (int r = 0; r < 16; r++) {
        const int rl = (r & 3) + 8 * (r >> 2) + 4 * half;
        sm[wn * 128 + wm * 64 + mt * 32 + rl] = q2[mt][r];
      }
  }
  __syncthreads();
  if (tid < 128)
    sm[640 + tid] = rsqrtf(
        (sm[tid] + sm[128 + tid] + sm[256 + tid] + sm[384 + tid]) * (1.f / 256.f) + 1e-5f);
  __syncthreads();
  float4 iv4[2][4];
#pragma unroll
  for (int mt = 0; mt < 2; mt++)
#pragma unroll
    for (int g = 0; g < 4; g++)
      iv4[mt][g] = *(const float4*)(sm + 640 + wm * 64 + mt * 32 + g * 8 + 4 * half);

  const float g0 = gam[col0], g1 = gam[col0 + 32];
  const float e0 = bet[col0], e1 = bet[col0 + 32];
  if constexpr (EPI == 1) {
#pragma unroll
    for (int mt = 0; mt < 2; mt++)
#pragma unroll
      for (int r = 0; r < 16; r++) {
        const float mu = ((const float*)&mu4[mt][r >> 2])[r & 3];
        const float iv = ((const float*)&iv4[mt][r >> 2])[r & 3];
        const int rl = (r & 3) + 8 * (r >> 2) + 4 * half;
        const long long row = (long long)m0 + wm * 64 + mt * 32 + rl;
        const float y0 = fmaxf((acc[mt][0][r] - mu) * iv * g0 + e0, 0.f);
        const float y1 = fmaxf((acc[mt][1][r] - mu) * iv * g1 + e1, 0.f);
        Cb[sC * bz + row * ldc + col0]      = (u16)f2bf(y0);
        Cb[sC * bz + row * ldc + col0 + 32] = (u16)f2bf(y1);
      }
  } else {
    float c0 = 0.f, c1 = 0.f;
#pragma unroll
    for (int mt = 0; mt < 2; mt++)
#pragma unroll
      for (int r = 0; r < 16; r++) {
        const float mu = ((const float*)&mu4[mt][r >> 2])[r & 3];
        const float iv = ((const float*)&iv4[mt][r >> 2])[r & 3];
        c0 += fmaxf((acc[mt][0][r] - mu) * iv * g0 + e0, 0.f);
        c1 += fmaxf((acc[mt][1][r] - mu) * iv * g1 + e1, 0.f);
      }
    c0 += __shfl_xor(c0, 32);
    c1 += __shfl_xor(c1, 32);
    if (half == 0) {
      atomicAdd(gcn + bz * 256 + col0, c0);
      atomicAdd(gcn + bz * 256 + col0 + 32, c1);
    }
  }
}

// fp32 -> bf16, 8 elems/thread
__global__ __launch_bounds__(256) void convert_bf16(const float* __restrict__ in,
                                                    u16* __restrict__ out, long long n8)
{
  const long long i = (long long)blockIdx.x * 256 + threadIdx.x;
  if (i >= n8) return;
  const float4 a = ((const float4*)in)[2 * i];
  const float4 b = ((const float4*)in)[2 * i + 1];
  uint4 r;
  r.x = f2bf(a.x) | (f2bf(a.y) << 16);
  r.y = f2bf(a.z) | (f2bf(a.w) << 16);
  r.z = f2bf(b.x) | (f2bf(b.y) << 16);
  r.w = f2bf(b.z) | (f2bf(b.w) << 16);
  ((uint4*)out)[i] = r;
}

__global__ __launch_bounds__(256) void transpose_bf16(const float* __restrict__ in,
                                                      u16* __restrict__ outp,
                                                      int rows, int cols)
{
  const int n = rows * cols;
  const int o = blockIdx.x * 256 + threadIdx.x;
  if (o < n) {
    const int c = o / rows, r = o - c * rows;
    outp[o] = (u16)f2bf(in[r * cols + c]);
  }
}

__global__ void zero_kernel(float* p, int n) {
  const int i = blockIdx.x * 256 + threadIdx.x;
  if (i < n) p[i] = 0.f;
}

// fused readout: fused=[gcn/2048, gv]; pred_y=fused@Ws+bs; pred_arr=fused@Wa+ba
__global__ __launch_bounds__(128) void final_kernel(
    const float* __restrict__ gcn, const float* __restrict__ gv,
    const float* __restrict__ Ws, const float* __restrict__ bs,
    const float* __restrict__ Wa, const float* __restrict__ ba,
    float* __restrict__ out)
{
  const int b = blockIdx.x, t = threadIdx.x;
  __shared__ float fused[274];
  fused[t] = gcn[b * 256 + t] * (1.f / 2048.f);
  fused[128 + t] = gcn[b * 256 + 128 + t] * (1.f / 2048.f);
  if (t < 18) fused[256 + t] = gv[b * 18 + t];
  __syncthreads();
  float acc = ba[t];
  for (int i = 0; i < 274; i++) acc = fmaf(fused[i], Wa[i * 128 + t], acc);
  out[16 + b * 128 + t] = acc;
  if (t < 64) {
    float p = 0.f;
    for (int i = t; i < 274; i += 64) p += fused[i] * Ws[i];
#pragma unroll
    for (int off = 32; off >= 1; off >>= 1) p += __shfl_xor(p, off);
    if (t == 0) out[b] = p + bs[0];
  }
}

extern "C" void kernel_launch(void* const* d_in, const int* in_sizes, int n_in,
                              void* d_out, int out_size, void* d_ws, size_t ws_size,
                              hipStream_t stream)
{
  const float* A   = (const float*)d_in[0];   // (16,2048,2048)
  const float* X   = (const float*)d_in[1];   // (16,2048,64)
  const float* GV  = (const float*)d_in[2];   // (16,18)
  const float* W1  = (const float*)d_in[3];   // (64,256)
  const float* b1  = (const float*)d_in[4];
  const float* g1  = (const float*)d_in[5];
  const float* be1 = (const float*)d_in[6];
  const float* W2  = (const float*)d_in[7];   // (256,256)
  const float* b2  = (const float*)d_in[8];
  const float* g2  = (const float*)d_in[9];
  const float* be2 = (const float*)d_in[10];
  const float* Ws  = (const float*)d_in[11];  // (274,1)
  const float* bs  = (const float*)d_in[12];
  const float* Wa  = (const float*)d_in[13];  // (274,128)
  const float* ba  = (const float*)d_in[14];
  float* out = (float*)d_out;
  (void)in_sizes; (void)n_in; (void)out_size; (void)ws_size;

  char* ws = (char*)d_ws;                  // needs 188,923,904 B (1 GiB observed)
  u16*   Abf = (u16*)(ws + 0);             // 134,217,728 B (16,2048,2048) bf16
  u16*   Xbf = (u16*)(ws + 134217728);     //   4,194,304 B (16,2048,64)
  u16*   W1T = (u16*)(ws + 138412032);     //      32,768 B (256,64)
  u16*   W2T = (u16*)(ws + 138444800);     //     131,072 B (256,256)
  u16*   XWT = (u16*)(ws + 138575872);     //  16,777,216 B (16,256,2048) = (X@W1)^T
  u16*   H1  = (u16*)(ws + 155353088);     //  16,777,216 B (16,2048,256)
  u16*   HWT = (u16*)(ws + 172130304);     //  16,777,216 B (16,256,2048) = (H1@W2)^T
  float* GCN = (float*)(ws + 188907520);   //      16,384 B (16,256)

  zero_kernel<<<16, 256, 0, stream>>>(GCN, 4096);
  convert_bf16<<<1024, 256, 0, stream>>>(X, Xbf, 262144LL);
  transpose_bf16<<<64, 256, 0, stream>>>(W1, W1T, 64, 256);
  transpose_bf16<<<256, 256, 0, stream>>>(W2, W2T, 256, 256);
  convert_bf16<<<32768, 256, 0, stream>>>(A, Abf, 8388608LL);

  // XWT = (X@W1)^T:  A-op = W1T (256x64), B-op = Xbf (nodes x 64)
  mm128<0><<<dim3(2, 8, 16), 512, 0, stream>>>(
      W1T, Xbf, 64, 64, 64, 2048, 0LL, 131072LL, 524288LL,
      nullptr, nullptr, nullptr, XWT, nullptr);

  // H1 = relu(LN(A @ (X@W1) + b1)):  A-op = Abf, B-op = XWT
  mm128<1><<<dim3(16, 1, 16), 512, 0, stream>>>(
      Abf, XWT, 2048, 2048, 2048, 256, 4194304LL, 524288LL, 524288LL,
      b1, g1, be1, H1, nullptr);

  // HWT = (H1@W2)^T:  A-op = W2T (256x256), B-op = H1 (nodes x 256)
  mm128<0><<<dim3(2, 8, 16), 512, 0, stream>>>(
      W2T, H1, 256, 256, 256, 2048, 0LL, 524288LL, 524288LL,
      nullptr, nullptr, nullptr, HWT, nullptr);

  // GCN[b][c] = sum_nodes relu(LN(A @ (H1@W2) + b2))
  mm128<2><<<dim3(16, 1, 16), 512, 0, stream>>>(
      Abf, HWT, 2048, 2048, 2048, 256, 4194304LL, 524288LL, 524288LL,
      b2, g2, be2, nullptr, GCN);

  final_kernel<<<16, 128, 0, stream>>>(GCN, GV, Ws, bs, Wa, ba, out);
}

// Round 2
// 599.705 us; speedup vs baseline: 1.0013x; 1.0006x over previous
//
#include <hip/hip_runtime.h>

typedef unsigned short u16;
typedef __attribute__((ext_vector_type(8))) short bf16x8;
typedef __attribute__((ext_vector_type(16))) float f32x16;

__device__ __forceinline__ unsigned f2bf(float f) {
  unsigned u = __float_as_uint(f);
  return (u + 0x7fffu + ((u >> 16) & 1u)) >> 16;  // RNE fp32 -> bf16 bits
}

// async global->LDS, 16B per lane. LDS dest is wave-uniform base + lane*16.
__device__ __forceinline__ void async16(const u16* g, u16* l) {
  __builtin_amdgcn_global_load_lds(
      (const __attribute__((address_space(1))) void*)g,
      (__attribute__((address_space(3))) void*)l, 16, 0, 0);
}

// ---------------------------------------------------------------------------
// One-shot prep kernel (replaces 5 launches): grid-stride over
//   A fp32->bf16 (8,388,608 x 16B), X fp32->bf16 (262,144 x 16B),
//   W1^T (64x256 -> 256x64), W2^T (256x256), GCN zero (4096 floats).
// ---------------------------------------------------------------------------
__global__ __launch_bounds__(256) void prep(
    const float* __restrict__ A, u16* __restrict__ Abf,
    const float* __restrict__ X, u16* __restrict__ Xbf,
    const float* __restrict__ W1, u16* __restrict__ W1T,
    const float* __restrict__ W2, u16* __restrict__ W2T,
    float* __restrict__ GCN)
{
  const long long gid = (long long)blockIdx.x * 256 + threadIdx.x;
  const long long stride = (long long)gridDim.x * 256;
  for (long long i = gid; i < 8388608LL; i += stride) {
    const float4 a = ((const float4*)A)[2 * i];
    const float4 b = ((const float4*)A)[2 * i + 1];
    uint4 r;
    r.x = f2bf(a.x) | (f2bf(a.y) << 16);
    r.y = f2bf(a.z) | (f2bf(a.w) << 16);
    r.z = f2bf(b.x) | (f2bf(b.y) << 16);
    r.w = f2bf(b.z) | (f2bf(b.w) << 16);
    ((uint4*)Abf)[i] = r;
  }
  for (long long i = gid; i < 262144LL; i += stride) {
    const float4 a = ((const float4*)X)[2 * i];
    const float4 b = ((const float4*)X)[2 * i + 1];
    uint4 r;
    r.x = f2bf(a.x) | (f2bf(a.y) << 16);
    r.y = f2bf(a.z) | (f2bf(a.w) << 16);
    r.z = f2bf(b.x) | (f2bf(b.y) << 16);
    r.w = f2bf(b.z) | (f2bf(b.w) << 16);
    ((uint4*)Xbf)[i] = r;
  }
  for (long long i = gid; i < 16384LL; i += stride) {   // W1T[c][r] = W1[r][c]
    const int c = (int)(i >> 6), r = (int)(i & 63);
    W1T[i] = (u16)f2bf(W1[r * 256 + c]);
  }
  for (long long i = gid; i < 65536LL; i += stride) {   // W2T[c][r] = W2[r][c]
    const int c = (int)(i >> 8), r = (int)(i & 255);
    W2T[i] = (u16)f2bf(W2[r * 256 + c]);
  }
  if (gid < 4096) GCN[gid] = 0.f;
}

// ---------------------------------------------------------------------------
// Pipelined MFMA GEMM: C[bz](M x 256-slice) = A[bz] @ B[bz]^T
//   A: m-major k-contiguous bf16 (lda), B: n-major k-contiguous bf16 (ldb).
//   BM=128, BN=256, BK=64, 512 thr (8 waves, 2Mx4N, each 64m x 64n),
//   mfma_32x32x16. A and B BOTH double-buffered (96 KB LDS, 1 block/CU);
//   counted s_waitcnt vmcnt(6) keeps the full next-tile prefetch in flight
//   across the whole compute phase. XOR chunk swizzle folded into the fetch.
//   XCD batch clustering: fid%8 == XCD; each XCD gets 2 whole batches.
// EPI: 0 = plain bf16 store; 1 = +bias,LN(256),ReLU -> bf16 store;
//      2 = +bias,LN(256),ReLU -> column sums atomicAdd into gcn.
// ---------------------------------------------------------------------------
template<int EPI>
__global__ __launch_bounds__(512, 2) void mm128(
    const u16* __restrict__ Aop, const u16* __restrict__ Bop,
    int K, int lda, int ldb, int ldc,
    long long sA, long long sB, long long sC,
    const float* __restrict__ bias, const float* __restrict__ gam,
    const float* __restrict__ bet, u16* __restrict__ Cb, float* __restrict__ gcn)
{
  __shared__ __align__(16) u16 As[2][128 * 64];   // 2 x 16 KB
  __shared__ __align__(16) u16 Bs[2][256 * 64];   // 2 x 32 KB
  const int tid = threadIdx.x;
  const int w = tid >> 6, lane = tid & 63, l31 = lane & 31, half = lane >> 5;
  const int wm = w >> 2, wn = w & 3;              // wave tile: 64m x 64n

  // XCD batch clustering (grid is always 16 batches, pb blocks per batch)
  const int fid = blockIdx.x + gridDim.x * (blockIdx.y + gridDim.y * blockIdx.z);
  const int pb = gridDim.x * gridDim.y;
  int idx = fid >> 3;
  int bz = fid & 7;
  if (idx >= pb) { bz += 8; idx -= pb; }
  const int m0 = (int)(idx % gridDim.x) * 128;
  const int n0 = (int)(idx / gridDim.x) * 256;

  // staging map: each call covers 64 rows; thread -> (row tid>>3, phys chunk tid&7),
  // logical chunk = phys ^ (row&7)
  const int srow = tid >> 3;
  const int clog = (tid & 7) ^ (srow & 7);
  const u16* Ag = Aop + sA * bz + (size_t)(m0 + srow) * lda + clog * 8;
  const u16* Bg = Bop + sB * bz + (size_t)(n0 + srow) * ldb + clog * 8;

  f32x16 acc[2][2];
#pragma unroll
  for (int i = 0; i < 2; i++)
#pragma unroll
    for (int j = 0; j < 2; j++)
#pragma unroll
      for (int r = 0; r < 16; r++) acc[i][j][r] = 0.f;

  const int niter = K >> 6;
  // prologue: tile 0 into buf 0 (6 loads/thread)
  {
    u16* Ad = As[0]; u16* Bd = Bs[0];
    async16(Ag, Ad + tid * 8);
    async16(Ag + (size_t)64 * lda, Ad + 4096 + tid * 8);
#pragma unroll
    for (int p = 0; p < 4; p++)
      async16(Bg + (size_t)(p * 64) * ldb, Bd + p * 4096 + tid * 8);
  }

  for (int i = 0; i < niter; i++) {
    if (i + 1 < niter) {                     // prefetch tile i+1, stays in flight
      const int k1 = (i + 1) << 6;
      u16* Ad = As[(i + 1) & 1]; u16* Bd = Bs[(i + 1) & 1];
      async16(Ag + k1, Ad + tid * 8);
      async16(Ag + (size_t)64 * lda + k1, Ad + 4096 + tid * 8);
#pragma unroll
      for (int p = 0; p < 4; p++)
        async16(Bg + (size_t)(p * 64) * ldb + k1, Bd + p * 4096 + tid * 8);
      __builtin_amdgcn_s_waitcnt(0x0F76);    // vmcnt(6): drain tile i, keep i+1
    } else {
      __builtin_amdgcn_s_waitcnt(0x0F70);    // vmcnt(0)
    }
    __builtin_amdgcn_s_barrier();            // tile i visible to all waves
    __asm__ volatile("" ::: "memory");
    const u16* Ab = As[i & 1];
    const u16* Bb = Bs[i & 1];
#pragma unroll
    for (int kk = 0; kk < 4; kk++) {
      const int pc = ((kk * 2 + half) ^ (l31 & 7)) * 8;
      const bf16x8 a0 = *(const bf16x8*)(Ab + (wm * 64 + l31) * 64 + pc);
      const bf16x8 a1 = *(const bf16x8*)(Ab + (wm * 64 + 32 + l31) * 64 + pc);
      const bf16x8 b0 = *(const bf16x8*)(Bb + (wn * 64 + l31) * 64 + pc);
      const bf16x8 b1 = *(const bf16x8*)(Bb + (wn * 64 + 32 + l31) * 64 + pc);
      acc[0][0] = __builtin_amdgcn_mfma_f32_32x32x16_bf16(a0, b0, acc[0][0], 0, 0, 0);
      acc[0][1] = __builtin_amdgcn_mfma_f32_32x32x16_bf16(a0, b1, acc[0][1], 0, 0, 0);
      acc[1][0] = __builtin_amdgcn_mfma_f32_32x32x16_bf16(a1, b0, acc[1][0], 0, 0, 0);
      acc[1][1] = __builtin_amdgcn_mfma_f32_32x32x16_bf16(a1, b1, acc[1][1], 0, 0, 0);
    }
    __asm__ volatile("" ::: "memory");
    __builtin_amdgcn_s_barrier();            // readers done before next overwrite
  }

  // C/D layout: col = wn*64 + nt*32 + l31; row_local = wm*64 + mt*32 + (r&3)+8*(r>>2)+4*half
  const int col0 = wn * 64 + l31;

  if constexpr (EPI == 0) {
#pragma unroll
    for (int mt = 0; mt < 2; mt++)
#pragma unroll
      for (int r = 0; r < 16; r++) {
        const int rl = (r & 3) + 8 * (r >> 2) + 4 * half;
        const long long row = (long long)m0 + wm * 64 + mt * 32 + rl;
        Cb[sC * bz + row * ldc + n0 + col0]      = (u16)f2bf(acc[mt][0][r]);
        Cb[sC * bz + row * ldc + n0 + col0 + 32] = (u16)f2bf(acc[mt][1][r]);
      }
    return;
  }

  // ---- LN epilogue (EPI 1/2): +bias, LN over 256 cols per row, ReLU ----
  __syncthreads();                           // full drain before As reuse as scratch
  const float bia0 = bias[col0], bia1 = bias[col0 + 32];
  float s2[2][16];
#pragma unroll
  for (int mt = 0; mt < 2; mt++)
#pragma unroll
    for (int r = 0; r < 16; r++) {
      acc[mt][0][r] += bia0;
      acc[mt][1][r] += bia1;
      s2[mt][r] = acc[mt][0][r] + acc[mt][1][r];
    }
#pragma unroll
  for (int off = 1; off <= 16; off <<= 1)
#pragma unroll
    for (int mt = 0; mt < 2; mt++)
#pragma unroll
      for (int r = 0; r < 16; r++) s2[mt][r] += __shfl_xor(s2[mt][r], off);

  // scratch in As (8192 floats): rowp[4][128] @0, mu[128] @512, iv[128] @640
  float* sm = (float*)As;
  if (l31 == 0) {
#pragma unroll
    for (int mt = 0; mt < 2; mt++)
#pragma unroll
      for (int r = 0; r < 16; r++) {
        const int rl = (r & 3) + 8 * (r >> 2) + 4 * half;
        sm[wn * 128 + wm * 64 + mt * 32 + rl] = s2[mt][r];
      }
  }
  __syncthreads();
  if (tid < 128)
    sm[512 + tid] = (sm[tid] + sm[128 + tid] + sm[256 + tid] + sm[384 + tid]) * (1.f / 256.f);
  __syncthreads();
  float4 mu4[2][4];
#pragma unroll
  for (int mt = 0; mt < 2; mt++)
#pragma unroll
    for (int g = 0; g < 4; g++)
      mu4[mt][g] = *(const float4*)(sm + 512 + wm * 64 + mt * 32 + g * 8 + 4 * half);

  float q2[2][16];
#pragma unroll
  for (int mt = 0; mt < 2; mt++)
#pragma unroll
    for (int r = 0; r < 16; r++) {
      const float mu = ((const float*)&mu4[mt][r >> 2])[r & 3];
      const float d0 = acc[mt][0][r] - mu, d1 = acc[mt][1][r] - mu;
      q2[mt][r] = d0 * d0 + d1 * d1;
    }
#pragma unroll
  for (int off = 1; off <= 16; off <<= 1)
#pragma unroll
    for (int mt = 0; mt < 2; mt++)
#pragma unroll
      for (int r = 0; r < 16; r++) q2[mt][r] += __shfl_xor(q2[mt][r], off);
  __syncthreads();
  if (l31 == 0) {
#pragma unroll
    for (int mt = 0; mt < 2; mt++)
#pragma unroll
      for (int r = 0; r < 16; r++) {
        const int rl = (r & 3) + 8 * (r >> 2) + 4 * half;
        sm[wn * 128 + wm * 64 + mt * 32 + rl] = q2[mt][r];
      }
  }
  __syncthreads();
  if (tid < 128)
    sm[640 + tid] = rsqrtf(
        (sm[tid] + sm[128 + tid] + sm[256 + tid] + sm[384 + tid]) * (1.f / 256.f) + 1e-5f);
  __syncthreads();
  float4 iv4[2][4];
#pragma unroll
  for (int mt = 0; mt < 2; mt++)
#pragma unroll
    for (int g = 0; g < 4; g++)
      iv4[mt][g] = *(const float4*)(sm + 640 + wm * 64 + mt * 32 + g * 8 + 4 * half);

  const float g0 = gam[col0], g1 = gam[col0 + 32];
  const float e0 = bet[col0], e1 = bet[col0 + 32];
  if constexpr (EPI == 1) {
#pragma unroll
    for (int mt = 0; mt < 2; mt++)
#pragma unroll
      for (int r = 0; r < 16; r++) {
        const float mu = ((const float*)&mu4[mt][r >> 2])[r & 3];
        const float iv = ((const float*)&iv4[mt][r >> 2])[r & 3];
        const int rl = (r & 3) + 8 * (r >> 2) + 4 * half;
        const long long row = (long long)m0 + wm * 64 + mt * 32 + rl;
        const float y0 = fmaxf((acc[mt][0][r] - mu) * iv * g0 + e0, 0.f);
        const float y1 = fmaxf((acc[mt][1][r] - mu) * iv * g1 + e1, 0.f);
        Cb[sC * bz + row * ldc + col0]      = (u16)f2bf(y0);
        Cb[sC * bz + row * ldc + col0 + 32] = (u16)f2bf(y1);
      }
  } else {
    float c0 = 0.f, c1 = 0.f;
#pragma unroll
    for (int mt = 0; mt < 2; mt++)
#pragma unroll
      for (int r = 0; r < 16; r++) {
        const float mu = ((const float*)&mu4[mt][r >> 2])[r & 3];
        const float iv = ((const float*)&iv4[mt][r >> 2])[r & 3];
        c0 += fmaxf((acc[mt][0][r] - mu) * iv * g0 + e0, 0.f);
        c1 += fmaxf((acc[mt][1][r] - mu) * iv * g1 + e1, 0.f);
      }
    c0 += __shfl_xor(c0, 32);
    c1 += __shfl_xor(c1, 32);
    if (half == 0) {
      atomicAdd(gcn + bz * 256 + col0, c0);
      atomicAdd(gcn + bz * 256 + col0 + 32, c1);
    }
  }
}

// fused readout: fused=[gcn/2048, gv]; pred_y=fused@Ws+bs; pred_arr=fused@Wa+ba
__global__ __launch_bounds__(128) void final_kernel(
    const float* __restrict__ gcn, const float* __restrict__ gv,
    const float* __restrict__ Ws, const float* __restrict__ bs,
    const float* __restrict__ Wa, const float* __restrict__ ba,
    float* __restrict__ out)
{
  const int b = blockIdx.x, t = threadIdx.x;
  __shared__ float fused[274];
  fused[t] = gcn[b * 256 + t] * (1.f / 2048.f);
  fused[128 + t] = gcn[b * 256 + 128 + t] * (1.f / 2048.f);
  if (t < 18) fused[256 + t] = gv[b * 18 + t];
  __syncthreads();
  float acc = ba[t];
  for (int i = 0; i < 274; i++) acc = fmaf(fused[i], Wa[i * 128 + t], acc);
  out[16 + b * 128 + t] = acc;
  if (t < 64) {
    float p = 0.f;
    for (int i = t; i < 274; i += 64) p += fused[i] * Ws[i];
#pragma unroll
    for (int off = 32; off >= 1; off >>= 1) p += __shfl_xor(p, off);
    if (t == 0) out[b] = p + bs[0];
  }
}

extern "C" void kernel_launch(void* const* d_in, const int* in_sizes, int n_in,
                              void* d_out, int out_size, void* d_ws, size_t ws_size,
                              hipStream_t stream)
{
  const float* A   = (const float*)d_in[0];   // (16,2048,2048)
  const float* X   = (const float*)d_in[1];   // (16,2048,64)
  const float* GV  = (const float*)d_in[2];   // (16,18)
  const float* W1  = (const float*)d_in[3];   // (64,256)
  const float* b1  = (const float*)d_in[4];
  const float* g1  = (const float*)d_in[5];
  const float* be1 = (const float*)d_in[6];
  const float* W2  = (const float*)d_in[7];   // (256,256)
  const float* b2  = (const float*)d_in[8];
  const float* g2  = (const float*)d_in[9];
  const float* be2 = (const float*)d_in[10];
  const float* Ws  = (const float*)d_in[11];  // (274,1)
  const float* bs  = (const float*)d_in[12];
  const float* Wa  = (const float*)d_in[13];  // (274,128)
  const float* ba  = (const float*)d_in[14];
  float* out = (float*)d_out;
  (void)in_sizes; (void)n_in; (void)out_size; (void)ws_size;

  char* ws = (char*)d_ws;                  // needs 188,923,904 B (1 GiB observed)
  u16*   Abf = (u16*)(ws + 0);             // 134,217,728 B (16,2048,2048) bf16
  u16*   Xbf = (u16*)(ws + 134217728);     //   4,194,304 B (16,2048,64)
  u16*   W1T = (u16*)(ws + 138412032);     //      32,768 B (256,64)
  u16*   W2T = (u16*)(ws + 138444800);     //     131,072 B (256,256)
  u16*   XWT = (u16*)(ws + 138575872);     //  16,777,216 B (16,256,2048) = (X@W1)^T
  u16*   H1  = (u16*)(ws + 155353088);     //  16,777,216 B (16,2048,256)
  u16*   HWT = (u16*)(ws + 172130304);     //  16,777,216 B (16,256,2048) = (H1@W2)^T
  float* GCN = (float*)(ws + 188907520);   //      16,384 B (16,256)

  // single prep launch: A/X bf16 convert, W1^T, W2^T, GCN zero
  prep<<<4096, 256, 0, stream>>>(A, Abf, X, Xbf, W1, W1T, W2, W2T, GCN);

  // XWT = (X@W1)^T:  A-op = W1T (256x64), B-op = Xbf (nodes x 64)
  mm128<0><<<dim3(2, 8, 16), 512, 0, stream>>>(
      W1T, Xbf, 64, 64, 64, 2048, 0LL, 131072LL, 524288LL,
      nullptr, nullptr, nullptr, XWT, nullptr);

  // H1 = relu(LN(A @ (X@W1) + b1)):  A-op = Abf, B-op = XWT
  mm128<1><<<dim3(16, 1, 16), 512, 0, stream>>>(
      Abf, XWT, 2048, 2048, 2048, 256, 4194304LL, 524288LL, 524288LL,
      b1, g1, be1, H1, nullptr);

  // HWT = (H1@W2)^T:  A-op = W2T (256x256), B-op = H1 (nodes x 256)
  mm128<0><<<dim3(2, 8, 16), 512, 0, stream>>>(
      W2T, H1, 256, 256, 256, 2048, 0LL, 524288LL, 524288LL,
      nullptr, nullptr, nullptr, HWT, nullptr);

  // GCN[b][c] = sum_nodes relu(LN(A @ (H1@W2) + b2))
  mm128<2><<<dim3(16, 1, 16), 512, 0, stream>>>(
      Abf, HWT, 2048, 2048, 2048, 256, 4194304LL, 524288LL, 524288LL,
      b2, g2, be2, nullptr, GCN);

  final_kernel<<<16, 128, 0, stream>>>(GCN, GV, Ws, bs, Wa, ba, out);
}

// Round 4
// 592.250 us; speedup vs baseline: 1.0139x; 1.0126x over previous
//
#include <hip/hip_runtime.h>

typedef unsigned short u16;
typedef __attribute__((ext_vector_type(8))) short bf16x8;
typedef __attribute__((ext_vector_type(16))) float f32x16;

__device__ __forceinline__ unsigned f2bf(float f) {
  unsigned u = __float_as_uint(f);
  return (u + 0x7fffu + ((u >> 16) & 1u)) >> 16;  // RNE fp32 -> bf16 bits
}

// async global->LDS, 16B per lane. LDS dest is wave-uniform base + lane*16.
__device__ __forceinline__ void async16(const u16* g, u16* l) {
  __builtin_amdgcn_global_load_lds(
      (const __attribute__((address_space(1))) void*)g,
      (__attribute__((address_space(3))) void*)l, 16, 0, 0);
}

// ---------------------------------------------------------------------------
// One-shot prep kernel: grid-stride over
//   A fp32->bf16 (8,388,608 x 16B), X fp32->bf16 (262,144 x 16B),
//   W1^T (64x256 -> 256x64), W2^T (256x256), GCN zero (4096 floats).
// ---------------------------------------------------------------------------
__global__ __launch_bounds__(256) void prep(
    const float* __restrict__ A, u16* __restrict__ Abf,
    const float* __restrict__ X, u16* __restrict__ Xbf,
    const float* __restrict__ W1, u16* __restrict__ W1T,
    const float* __restrict__ W2, u16* __restrict__ W2T,
    float* __restrict__ GCN)
{
  const long long gid = (long long)blockIdx.x * 256 + threadIdx.x;
  const long long stride = (long long)gridDim.x * 256;
  for (long long i = gid; i < 8388608LL; i += stride) {
    const float4 a = ((const float4*)A)[2 * i];
    const float4 b = ((const float4*)A)[2 * i + 1];
    uint4 r;
    r.x = f2bf(a.x) | (f2bf(a.y) << 16);
    r.y = f2bf(a.z) | (f2bf(a.w) << 16);
    r.z = f2bf(b.x) | (f2bf(b.y) << 16);
    r.w = f2bf(b.z) | (f2bf(b.w) << 16);
    ((uint4*)Abf)[i] = r;
  }
  for (long long i = gid; i < 262144LL; i += stride) {
    const float4 a = ((const float4*)X)[2 * i];
    const float4 b = ((const float4*)X)[2 * i + 1];
    uint4 r;
    r.x = f2bf(a.x) | (f2bf(a.y) << 16);
    r.y = f2bf(a.z) | (f2bf(a.w) << 16);
    r.z = f2bf(b.x) | (f2bf(b.y) << 16);
    r.w = f2bf(b.z) | (f2bf(b.w) << 16);
    ((uint4*)Xbf)[i] = r;
  }
  for (long long i = gid; i < 16384LL; i += stride) {   // W1T[c][r] = W1[r][c]
    const int c = (int)(i >> 6), r = (int)(i & 63);
    W1T[i] = (u16)f2bf(W1[r * 256 + c]);
  }
  for (long long i = gid; i < 65536LL; i += stride) {   // W2T[c][r] = W2[r][c]
    const int c = (int)(i >> 8), r = (int)(i & 255);
    W2T[i] = (u16)f2bf(W2[r * 256 + c]);
  }
  if (gid < 4096) GCN[gid] = 0.f;
}

// ---------------------------------------------------------------------------
// Pipelined MFMA GEMM: C[bz](M x 256-slice) = A[bz] @ B[bz]^T
//   A: m-major k-contiguous bf16 (lda), B: n-major k-contiguous bf16 (ldb).
//   BM=128, BN=256, BK=64, 512 thr (8 waves, 2Mx4N, each 64m x 64n),
//   mfma_32x32x16. A and B double-buffered (96 KB LDS, 1 block/CU);
//   counted s_waitcnt vmcnt(6). XOR chunk swizzle folded into the fetch.
//   XCD batch clustering: fid%8 == XCD; each XCD gets 2 whole batches.
// EPI: 0 = plain bf16 store
//      1 = +bias,LN(256),ReLU -> bf16 store (unused)
//      2 = +bias,LN(256),ReLU -> column sums atomicAdd into gcn
//      3 = +bias,LN(256),ReLU -> keep bf16 tile in LDS, then fused
//          HWT-slice GEMM: out[256x128] = W2T(256x256) @ Htile^T, store to Cb
//          (eliminates the H1 global round-trip + a separate launch)
// ---------------------------------------------------------------------------
template<int EPI>
__global__ __launch_bounds__(512, 2) void mm128(
    const u16* __restrict__ Aop, const u16* __restrict__ Bop,
    int K, int lda, int ldb, int ldc,
    long long sA, long long sB, long long sC,
    const float* __restrict__ bias, const float* __restrict__ gam,
    const float* __restrict__ bet, u16* __restrict__ Cb, float* __restrict__ gcn,
    const u16* __restrict__ W2x)
{
  __shared__ __align__(16) u16 As[2][128 * 64];   // 2 x 16 KB
  __shared__ __align__(16) u16 Bs[2][256 * 64];   // 2 x 32 KB
  const int tid = threadIdx.x;
  const int w = tid >> 6, lane = tid & 63, l31 = lane & 31, half = lane >> 5;
  const int wm = w >> 2, wn = w & 3;              // wave tile: 64m x 64n

  // XCD batch clustering (grid is always 16 batches, pb blocks per batch)
  const int fid = blockIdx.x + gridDim.x * (blockIdx.y + gridDim.y * blockIdx.z);
  const int pb = gridDim.x * gridDim.y;
  int idx = fid >> 3;
  int bz = fid & 7;
  if (idx >= pb) { bz += 8; idx -= pb; }
  const int m0 = (int)(idx % gridDim.x) * 128;
  const int n0 = (int)(idx / gridDim.x) * 256;

  // staging map: each call covers 64 rows; thread -> (row tid>>3, phys chunk tid&7),
  // logical chunk = phys ^ (row&7)
  const int srow = tid >> 3;
  const int clog = (tid & 7) ^ (srow & 7);
  const u16* Ag = Aop + sA * bz + (size_t)(m0 + srow) * lda + clog * 8;
  const u16* Bg = Bop + sB * bz + (size_t)(n0 + srow) * ldb + clog * 8;

  f32x16 acc[2][2];
#pragma unroll
  for (int i = 0; i < 2; i++)
#pragma unroll
    for (int j = 0; j < 2; j++)
#pragma unroll
      for (int r = 0; r < 16; r++) acc[i][j][r] = 0.f;

  const int niter = K >> 6;
  // prologue: tile 0 into buf 0 (6 loads/thread)
  {
    u16* Ad = As[0]; u16* Bd = Bs[0];
    async16(Ag, Ad + tid * 8);
    async16(Ag + (size_t)64 * lda, Ad + 4096 + tid * 8);
#pragma unroll
    for (int p = 0; p < 4; p++)
      async16(Bg + (size_t)(p * 64) * ldb, Bd + p * 4096 + tid * 8);
  }

  for (int i = 0; i < niter; i++) {
    if (i + 1 < niter) {                     // prefetch tile i+1, stays in flight
      const int k1 = (i + 1) << 6;
      u16* Ad = As[(i + 1) & 1]; u16* Bd = Bs[(i + 1) & 1];
      async16(Ag + k1, Ad + tid * 8);
      async16(Ag + (size_t)64 * lda + k1, Ad + 4096 + tid * 8);
#pragma unroll
      for (int p = 0; p < 4; p++)
        async16(Bg + (size_t)(p * 64) * ldb + k1, Bd + p * 4096 + tid * 8);
      __builtin_amdgcn_s_waitcnt(0x0F76);    // vmcnt(6): drain tile i, keep i+1
    } else {
      __builtin_amdgcn_s_waitcnt(0x0F70);    // vmcnt(0)
    }
    __builtin_amdgcn_s_barrier();            // tile i visible to all waves
    __asm__ volatile("" ::: "memory");
    const u16* Ab = As[i & 1];
    const u16* Bb = Bs[i & 1];
#pragma unroll
    for (int kk = 0; kk < 4; kk++) {
      const int pc = ((kk * 2 + half) ^ (l31 & 7)) * 8;
      const bf16x8 a0 = *(const bf16x8*)(Ab + (wm * 64 + l31) * 64 + pc);
      const bf16x8 a1 = *(const bf16x8*)(Ab + (wm * 64 + 32 + l31) * 64 + pc);
      const bf16x8 b0 = *(const bf16x8*)(Bb + (wn * 64 + l31) * 64 + pc);
      const bf16x8 b1 = *(const bf16x8*)(Bb + (wn * 64 + 32 + l31) * 64 + pc);
      acc[0][0] = __builtin_amdgcn_mfma_f32_32x32x16_bf16(a0, b0, acc[0][0], 0, 0, 0);
      acc[0][1] = __builtin_amdgcn_mfma_f32_32x32x16_bf16(a0, b1, acc[0][1], 0, 0, 0);
      acc[1][0] = __builtin_amdgcn_mfma_f32_32x32x16_bf16(a1, b0, acc[1][0], 0, 0, 0);
      acc[1][1] = __builtin_amdgcn_mfma_f32_32x32x16_bf16(a1, b1, acc[1][1], 0, 0, 0);
    }
    __asm__ volatile("" ::: "memory");
    __builtin_amdgcn_s_barrier();            // readers done before next overwrite
  }

  // C/D layout: col = wn*64 + nt*32 + l31; row_local = wm*64 + mt*32 + (r&3)+8*(r>>2)+4*half
  const int col0 = wn * 64 + l31;

  if constexpr (EPI == 0) {
#pragma unroll
    for (int mt = 0; mt < 2; mt++)
#pragma unroll
      for (int r = 0; r < 16; r++) {
        const int rl = (r & 3) + 8 * (r >> 2) + 4 * half;
        const long long row = (long long)m0 + wm * 64 + mt * 32 + rl;
        Cb[sC * bz + row * ldc + n0 + col0]      = (u16)f2bf(acc[mt][0][r]);
        Cb[sC * bz + row * ldc + n0 + col0 + 32] = (u16)f2bf(acc[mt][1][r]);
      }
    return;
  }

  // ---- LN epilogue (EPI 1/2/3): +bias, LN over 256 cols per row, ReLU ----
  __syncthreads();                           // full drain before As reuse as scratch
  const float bia0 = bias[col0], bia1 = bias[col0 + 32];
  float s2[2][16];
#pragma unroll
  for (int mt = 0; mt < 2; mt++)
#pragma unroll
    for (int r = 0; r < 16; r++) {
      acc[mt][0][r] += bia0;
      acc[mt][1][r] += bia1;
      s2[mt][r] = acc[mt][0][r] + acc[mt][1][r];
    }
#pragma unroll
  for (int off = 1; off <= 16; off <<= 1)
#pragma unroll
    for (int mt = 0; mt < 2; mt++)
#pragma unroll
      for (int r = 0; r < 16; r++) s2[mt][r] += __shfl_xor(s2[mt][r], off);

  // scratch in As (floats): rowp[4][128] @0, mu[128] @512, iv[128] @640
  float* sm = (float*)As;
  if (l31 == 0) {
#pragma unroll
    for (int mt = 0; mt < 2; mt++)
#pragma unroll
      for (int r = 0; r < 16; r++) {
        const int rl = (r & 3) + 8 * (r >> 2) + 4 * half;
        sm[wn * 128 + wm * 64 + mt * 32 + rl] = s2[mt][r];
      }
  }
  __syncthreads();
  if (tid < 128)
    sm[512 + tid] = (sm[tid] + sm[128 + tid] + sm[256 + tid] + sm[384 + tid]) * (1.f / 256.f);
  __syncthreads();
  float4 mu4[2][4];
#pragma unroll
  for (int mt = 0; mt < 2; mt++)
#pragma unroll
    for (int g = 0; g < 4; g++)
      mu4[mt][g] = *(const float4*)(sm + 512 + wm * 64 + mt * 32 + g * 8 + 4 * half);

  float q2[2][16];
#pragma unroll
  for (int mt = 0; mt < 2; mt++)
#pragma unroll
    for (int r = 0; r < 16; r++) {
      const float mu = ((const float*)&mu4[mt][r >> 2])[r & 3];
      const float d0 = acc[mt][0][r] - mu, d1 = acc[mt][1][r] - mu;
      q2[mt][r] = d0 * d0 + d1 * d1;
    }
#pragma unroll
  for (int off = 1; off <= 16; off <<= 1)
#pragma unroll
    for (int mt = 0; mt < 2; mt++)
#pragma unroll
      for (int r = 0; r < 16; r++) q2[mt][r] += __shfl_xor(q2[mt][r], off);
  __syncthreads();
  if (l31 == 0) {
#pragma unroll
    for (int mt = 0; mt < 2; mt++)
#pragma unroll
      for (int r = 0; r < 16; r++) {
        const int rl = (r & 3) + 8 * (r >> 2) + 4 * half;
        sm[wn * 128 + wm * 64 + mt * 32 + rl] = q2[mt][r];
      }
  }
  __syncthreads();
  if (tid < 128)
    sm[640 + tid] = rsqrtf(
        (sm[tid] + sm[128 + tid] + sm[256 + tid] + sm[384 + tid]) * (1.f / 256.f) + 1e-5f);
  __syncthreads();
  float4 iv4[2][4];
#pragma unroll
  for (int mt = 0; mt < 2; mt++)
#pragma unroll
    for (int g = 0; g < 4; g++)
      iv4[mt][g] = *(const float4*)(sm + 640 + wm * 64 + mt * 32 + g * 8 + 4 * half);

  const float g0 = gam[col0], g1 = gam[col0 + 32];
  const float e0 = bet[col0], e1 = bet[col0 + 32];
  if constexpr (EPI == 1) {
#pragma unroll
    for (int mt = 0; mt < 2; mt++)
#pragma unroll
      for (int r = 0; r < 16; r++) {
        const float mu = ((const float*)&mu4[mt][r >> 2])[r & 3];
        const float iv = ((const float*)&iv4[mt][r >> 2])[r & 3];
        const int rl = (r & 3) + 8 * (r >> 2) + 4 * half;
        const long long row = (long long)m0 + wm * 64 + mt * 32 + rl;
        const float y0 = fmaxf((acc[mt][0][r] - mu) * iv * g0 + e0, 0.f);
        const float y1 = fmaxf((acc[mt][1][r] - mu) * iv * g1 + e1, 0.f);
        Cb[sC * bz + row * ldc + col0]      = (u16)f2bf(y0);
        Cb[sC * bz + row * ldc + col0 + 32] = (u16)f2bf(y1);
      }
  } else if constexpr (EPI == 2) {
    float c0 = 0.f, c1 = 0.f;
#pragma unroll
    for (int mt = 0; mt < 2; mt++)
#pragma unroll
      for (int r = 0; r < 16; r++) {
        const float mu = ((const float*)&mu4[mt][r >> 2])[r & 3];
        const float iv = ((const float*)&iv4[mt][r >> 2])[r & 3];
        c0 += fmaxf((acc[mt][0][r] - mu) * iv * g0 + e0, 0.f);
        c1 += fmaxf((acc[mt][1][r] - mu) * iv * g1 + e1, 0.f);
      }
    c0 += __shfl_xor(c0, 32);
    c1 += __shfl_xor(c1, 32);
    if (half == 0) {
      atomicAdd(gcn + bz * 256 + col0, c0);
      atomicAdd(gcn + bz * 256 + col0 + 32, c1);
    }
  } else {
    // ---- EPI 3: H-tile (128x256 bf16) -> LDS, then HWT slice = W2T @ Htile^T ----
    // H1loc in Bs (64 KB): row-major [128][256], byte = row*512 + (col*2 ^ ((row&31)<<4))
    // (XOR swizzle breaks the 512B-stride bank conflict on k-contiguous reads)
    char* H1loc = (char*)Bs;
#pragma unroll
    for (int mt = 0; mt < 2; mt++)
#pragma unroll
      for (int r = 0; r < 16; r++) {
        const float mu = ((const float*)&mu4[mt][r >> 2])[r & 3];
        const float iv = ((const float*)&iv4[mt][r >> 2])[r & 3];
        const int rl = (r & 3) + 8 * (r >> 2) + 4 * half;
        const int row = wm * 64 + mt * 32 + rl;              // 0..127
        const float y0 = fmaxf((acc[mt][0][r] - mu) * iv * g0 + e0, 0.f);
        const float y1 = fmaxf((acc[mt][1][r] - mu) * iv * g1 + e1, 0.f);
        const int xo = (row & 31) << 4;
        *(u16*)(H1loc + row * 512 + ((col0 * 2) ^ xo))        = (u16)f2bf(y0);
        *(u16*)(H1loc + row * 512 + (((col0 + 32) * 2) ^ xo)) = (u16)f2bf(y1);
      }
    __syncthreads();   // H1loc complete; sm (As) reads done -> As reusable

    // mini-GEMM: out[o][m] = sum_k W2T[o][k] * Htile[m][k],  o in 0..255, m in 0..127
    // 8 waves: orow = (w>>1)*64 (4 row-groups), mcol = (w&1)*64 (2 col-groups)
    // W2T streamed through As as 8 x 16KB chunks (k = c*32..c*32+32), dbuf'd.
    u16* Wc = (u16*)As;                        // 2 x 8192 u16 chunk buffers
    const int orow = (w >> 1) * 64, mcol = (w & 1) * 64;
    const int srw2 = tid >> 2;                 // staging: 4 thr/row, 16B each
    const int cl2 = (tid & 3) ^ (srw2 & 3);    // logical 16B slot (phys = tid&3)

    f32x16 a2[2][2];
#pragma unroll
    for (int i = 0; i < 2; i++)
#pragma unroll
      for (int j = 0; j < 2; j++)
#pragma unroll
        for (int r = 0; r < 16; r++) a2[i][j][r] = 0.f;

#define STAGE_W2(c) do {                                                  \
    u16* _d = Wc + ((c) & 1) * 8192 + tid * 8;                            \
    const u16* _s = W2x + (size_t)srw2 * 256 + (c) * 32 + cl2 * 8;        \
    async16(_s, _d);                                                      \
    async16(_s + 128 * 256, _d + 4096);                                   \
  } while (0)

    STAGE_W2(0);
    STAGE_W2(1);
#pragma unroll
    for (int c = 0; c < 8; c++) {
      if (c < 7) __builtin_amdgcn_s_waitcnt(0x0F72);  // vmcnt(2): chunk c landed
      else       __builtin_amdgcn_s_waitcnt(0x0F70);  // vmcnt(0)
      __builtin_amdgcn_s_barrier();
      __asm__ volatile("" ::: "memory");
      const u16* bufc = Wc + (c & 1) * 8192;
#pragma unroll
      for (int kk = 0; kk < 2; kk++) {
        const int sl = kk * 2 + half;
        const int ao = (sl ^ (l31 & 3)) * 8;
        const bf16x8 a0 = *(const bf16x8*)(bufc + (orow + l31) * 32 + ao);
        const bf16x8 a1 = *(const bf16x8*)(bufc + (orow + 32 + l31) * 32 + ao);
        const int kb = (c * 32 + sl * 8) * 2;            // k byte offset
        const int xo = l31 << 4;
        const bf16x8 b0 = *(const bf16x8*)(H1loc + (mcol + l31) * 512 + (kb ^ xo));
        const bf16x8 b1 = *(const bf16x8*)(H1loc + (mcol + 32 + l31) * 512 + (kb ^ xo));
        a2[0][0] = __builtin_amdgcn_mfma_f32_32x32x16_bf16(a0, b0, a2[0][0], 0, 0, 0);
        a2[0][1] = __builtin_amdgcn_mfma_f32_32x32x16_bf16(a0, b1, a2[0][1], 0, 0, 0);
        a2[1][0] = __builtin_amdgcn_mfma_f32_32x32x16_bf16(a1, b0, a2[1][0], 0, 0, 0);
        a2[1][1] = __builtin_amdgcn_mfma_f32_32x32x16_bf16(a1, b1, a2[1][1], 0, 0, 0);
      }
      __asm__ volatile("" ::: "memory");
      __builtin_amdgcn_s_barrier();            // readers done before re-staging
      if (c + 2 < 8) STAGE_W2(c + 2);
    }
#undef STAGE_W2

    // store HWT slice: rows = W2T rows (0..255), cols = m0 + (0..127)
#pragma unroll
    for (int i = 0; i < 2; i++)
#pragma unroll
      for (int j = 0; j < 2; j++)
#pragma unroll
        for (int r = 0; r < 16; r++) {
          const int rl = (r & 3) + 8 * (r >> 2) + 4 * half;
          const long long rowo = orow + i * 32 + rl;
          const long long colg = m0 + mcol + j * 32 + l31;
          Cb[sC * bz + rowo * ldc + colg] = (u16)f2bf(a2[i][j][r]);
        }
  }
}

// fused readout: fused=[gcn/2048, gv]; pred_y=fused@Ws+bs; pred_arr=fused@Wa+ba
__global__ __launch_bounds__(128) void final_kernel(
    const float* __restrict__ gcn, const float* __restrict__ gv,
    const float* __restrict__ Ws, const float* __restrict__ bs,
    const float* __restrict__ Wa, const float* __restrict__ ba,
    float* __restrict__ out)
{
  const int b = blockIdx.x, t = threadIdx.x;
  __shared__ float fused[274];
  fused[t] = gcn[b * 256 + t] * (1.f / 2048.f);
  fused[128 + t] = gcn[b * 256 + 128 + t] * (1.f / 2048.f);
  if (t < 18) fused[256 + t] = gv[b * 18 + t];
  __syncthreads();
  float acc = ba[t];
  for (int i = 0; i < 274; i++) acc = fmaf(fused[i], Wa[i * 128 + t], acc);
  out[16 + b * 128 + t] = acc;
  if (t < 64) {
    float p = 0.f;
    for (int i = t; i < 274; i += 64) p += fused[i] * Ws[i];
#pragma unroll
    for (int off = 32; off >= 1; off >>= 1) p += __shfl_xor(p, off);
    if (t == 0) out[b] = p + bs[0];
  }
}

extern "C" void kernel_launch(void* const* d_in, const int* in_sizes, int n_in,
                              void* d_out, int out_size, void* d_ws, size_t ws_size,
                              hipStream_t stream)
{
  const float* A   = (const float*)d_in[0];   // (16,2048,2048)
  const float* X   = (const float*)d_in[1];   // (16,2048,64)
  const float* GV  = (const float*)d_in[2];   // (16,18)
  const float* W1  = (const float*)d_in[3];   // (64,256)
  const float* b1  = (const float*)d_in[4];
  const float* g1  = (const float*)d_in[5];
  const float* be1 = (const float*)d_in[6];
  const float* W2  = (const float*)d_in[7];   // (256,256)
  const float* b2  = (const float*)d_in[8];
  const float* g2  = (const float*)d_in[9];
  const float* be2 = (const float*)d_in[10];
  const float* Ws  = (const float*)d_in[11];  // (274,1)
  const float* bs  = (const float*)d_in[12];
  const float* Wa  = (const float*)d_in[13];  // (274,128)
  const float* ba  = (const float*)d_in[14];
  float* out = (float*)d_out;
  (void)in_sizes; (void)n_in; (void)out_size; (void)ws_size;

  char* ws = (char*)d_ws;
  u16*   Abf = (u16*)(ws + 0);             // 134,217,728 B (16,2048,2048) bf16
  u16*   Xbf = (u16*)(ws + 134217728);     //   4,194,304 B (16,2048,64)
  u16*   W1T = (u16*)(ws + 138412032);     //      32,768 B (256,64)
  u16*   W2T = (u16*)(ws + 138444800);     //     131,072 B (256,256)
  u16*   XWT = (u16*)(ws + 138575872);     //  16,777,216 B (16,256,2048) = (X@W1)^T
  u16*   HWT = (u16*)(ws + 155353088);     //  16,777,216 B (16,256,2048) = (H1@W2)^T
  float* GCN = (float*)(ws + 172130304);   //      16,384 B (16,256)

  // single prep launch: A/X bf16 convert, W1^T, W2^T, GCN zero
  prep<<<4096, 256, 0, stream>>>(A, Abf, X, Xbf, W1, W1T, W2, W2T, GCN);

  // XWT = (X@W1)^T:  A-op = W1T (256x64), B-op = Xbf (nodes x 64)
  mm128<0><<<dim3(2, 8, 16), 512, 0, stream>>>(
      W1T, Xbf, 64, 64, 64, 2048, 0LL, 131072LL, 524288LL,
      nullptr, nullptr, nullptr, XWT, nullptr, nullptr);

  // fused: H = relu(LN(A @ (X@W1) + b1)) kept in LDS; HWT = (H@W2)^T stored
  mm128<3><<<dim3(16, 1, 16), 512, 0, stream>>>(
      Abf, XWT, 2048, 2048, 2048, 2048, 4194304LL, 524288LL, 524288LL,
      b1, g1, be1, HWT, nullptr, W2T);

  // GCN[b][c] = sum_nodes relu(LN(A @ (H@W2) + b2))
  mm128<2><<<dim3(16, 1, 16), 512, 0, stream>>>(
      Abf, HWT, 2048, 2048, 2048, 256, 4194304LL, 524288LL, 524288LL,
      b2, g2, be2, nullptr, GCN, nullptr);

  final_kernel<<<16, 128, 0, stream>>>(GCN, GV, Ws, bs, Wa, ba, out);
}

// Round 5
// 568.109 us; speedup vs baseline: 1.0570x; 1.0425x over previous
//
#include <hip/hip_runtime.h>

typedef unsigned short u16;
typedef __attribute__((ext_vector_type(8))) short bf16x8;
typedef __attribute__((ext_vector_type(16))) float f32x16;

__device__ __forceinline__ unsigned f2bf(float f) {
  unsigned u = __float_as_uint(f);
  return (u + 0x7fffu + ((u >> 16) & 1u)) >> 16;  // RNE fp32 -> bf16 bits
}

// async global->LDS, 16B per lane. LDS dest is wave-uniform base + lane*16.
__device__ __forceinline__ void async16(const u16* g, u16* l) {
  __builtin_amdgcn_global_load_lds(
      (const __attribute__((address_space(1))) void*)g,
      (__attribute__((address_space(3))) void*)l, 16, 0, 0);
}

// ---------------------------------------------------------------------------
// Small prep kernel (A-convert moved into the first A-GEMM):
//   X fp32->bf16 (262,144 x 16B), W1^T (64x256 -> 256x64), W2^T (256x256),
//   GCN zero (4096 floats).
// ---------------------------------------------------------------------------
__global__ __launch_bounds__(256) void prep(
    const float* __restrict__ X, u16* __restrict__ Xbf,
    const float* __restrict__ W1, u16* __restrict__ W1T,
    const float* __restrict__ W2, u16* __restrict__ W2T,
    float* __restrict__ GCN)
{
  const long long gid = (long long)blockIdx.x * 256 + threadIdx.x;
  const long long stride = (long long)gridDim.x * 256;
  for (long long i = gid; i < 262144LL; i += stride) {
    const float4 a = ((const float4*)X)[2 * i];
    const float4 b = ((const float4*)X)[2 * i + 1];
    uint4 r;
    r.x = f2bf(a.x) | (f2bf(a.y) << 16);
    r.y = f2bf(a.z) | (f2bf(a.w) << 16);
    r.z = f2bf(b.x) | (f2bf(b.y) << 16);
    r.w = f2bf(b.z) | (f2bf(b.w) << 16);
    ((uint4*)Xbf)[i] = r;
  }
  for (long long i = gid; i < 16384LL; i += stride) {   // W1T[c][r] = W1[r][c]
    const int c = (int)(i >> 6), r = (int)(i & 63);
    W1T[i] = (u16)f2bf(W1[r * 256 + c]);
  }
  for (long long i = gid; i < 65536LL; i += stride) {   // W2T[c][r] = W2[r][c]
    const int c = (int)(i >> 8), r = (int)(i & 255);
    W2T[i] = (u16)f2bf(W2[r * 256 + c]);
  }
  if (gid < 4096) GCN[gid] = 0.f;
}

// ---------------------------------------------------------------------------
// Pipelined MFMA GEMM: C[bz](M x 256-slice) = A[bz] @ B[bz]^T
//   A: m-major k-contiguous bf16 (lda), B: n-major k-contiguous bf16 (ldb).
//   BM=128, BN=256, BK=64, 512 thr (8 waves, 2Mx4N, each 64m x 64n),
//   mfma_32x32x16. Double-buffered LDS; XOR chunk swizzle (phys = log ^ row&7).
//   XCD batch clustering: fid%8 == XCD; each XCD gets 2 whole batches.
// CVTA=1: A-operand staged from fp32 global with on-the-fly bf16 convert
//   (registers -> ds_write, same physical LDS layout) and the converted
//   panel is streamed out to AbfW for the second A-GEMM. vmcnt ledger:
//   steady {B(i)x4, St(i)x2} + issue {Ax4, Bx4} -> wait vmcnt(10)+lgkm(0)
//   drains B(i); post-MFMA vmcnt(4) frees A-regs/stores; last iter vmcnt(2).
// EPI: 0 = plain bf16 store
//      2 = +bias,LN(256),ReLU -> column sums atomicAdd into gcn
//      3 = +bias,LN(256),ReLU -> keep bf16 tile in LDS, then fused
//          HWT-slice GEMM: out[256x128] = W2T(256x256) @ Htile^T -> Cb
// ---------------------------------------------------------------------------
template<int EPI, int CVTA>
__global__ __launch_bounds__(512, 2) void mm128(
    const u16* __restrict__ Aop, const u16* __restrict__ Bop,
    int K, int lda, int ldb, int ldc,
    long long sA, long long sB, long long sC,
    const float* __restrict__ bias, const float* __restrict__ gam,
    const float* __restrict__ bet, u16* __restrict__ Cb, float* __restrict__ gcn,
    const u16* __restrict__ W2x, const float* __restrict__ Afp,
    u16* __restrict__ AbfW)
{
  __shared__ __align__(16) u16 As[2][128 * 64];   // 2 x 16 KB
  __shared__ __align__(16) u16 Bs[2][256 * 64];   // 2 x 32 KB
  const int tid = threadIdx.x;
  const int w = tid >> 6, lane = tid & 63, l31 = lane & 31, half = lane >> 5;
  const int wm = w >> 2, wn = w & 3;              // wave tile: 64m x 64n

  // XCD batch clustering (grid is always 16 batches, pb blocks per batch)
  const int fid = blockIdx.x + gridDim.x * (blockIdx.y + gridDim.y * blockIdx.z);
  const int pb = gridDim.x * gridDim.y;
  int idx = fid >> 3;
  int bz = fid & 7;
  if (idx >= pb) { bz += 8; idx -= pb; }
  const int m0 = (int)(idx % gridDim.x) * 128;
  const int n0 = (int)(idx / gridDim.x) * 256;

  // staging map: each call covers 64 rows; thread -> (row tid>>3, phys chunk tid&7),
  // logical chunk = phys ^ (row&7)
  const int srow = tid >> 3;
  const int clog = (tid & 7) ^ (srow & 7);
  const u16* Ag = Aop + sA * bz + (size_t)(m0 + srow) * lda + clog * 8;
  const u16* Bg = Bop + sB * bz + (size_t)(n0 + srow) * ldb + clog * 8;

  // CVTA path: linear logical chunk ch8 = tid&7; ds_write to phys = ch8^(row&7)
  const int ch8 = tid & 7;
  const float* Af = CVTA ? (Afp + sA * bz + (size_t)(m0 + srow) * lda + ch8 * 8) : nullptr;
  u16* Aw = CVTA ? (AbfW + sA * bz + (size_t)(m0 + srow) * lda + ch8 * 8) : nullptr;
  const int dsoff = srow * 64 + ((ch8 ^ (srow & 7)) * 8);  // u16 units

  float4 a4[4];
#define LOAD_A4(k) do {                                                   \
    a4[0] = *(const float4*)(Af + (k));                                   \
    a4[1] = *(const float4*)(Af + (k) + 4);                               \
    a4[2] = *(const float4*)(Af + (size_t)64 * lda + (k));                \
    a4[3] = *(const float4*)(Af + (size_t)64 * lda + (k) + 4);            \
  } while (0)
#define CVT_WRITE(dst, k) do {                                            \
    uint4 r0, r1;                                                         \
    r0.x = f2bf(a4[0].x) | (f2bf(a4[0].y) << 16);                         \
    r0.y = f2bf(a4[0].z) | (f2bf(a4[0].w) << 16);                         \
    r0.z = f2bf(a4[1].x) | (f2bf(a4[1].y) << 16);                         \
    r0.w = f2bf(a4[1].z) | (f2bf(a4[1].w) << 16);                         \
    r1.x = f2bf(a4[2].x) | (f2bf(a4[2].y) << 16);                         \
    r1.y = f2bf(a4[2].z) | (f2bf(a4[2].w) << 16);                         \
    r1.z = f2bf(a4[3].x) | (f2bf(a4[3].y) << 16);                         \
    r1.w = f2bf(a4[3].z) | (f2bf(a4[3].w) << 16);                         \
    *(uint4*)((dst) + dsoff)        = r0;                                 \
    *(uint4*)((dst) + 4096 + dsoff) = r1;                                 \
    *(uint4*)(Aw + (k))                      = r0;                        \
    *(uint4*)(Aw + (size_t)64 * lda + (k))   = r1;                        \
  } while (0)

  f32x16 acc[2][2];
#pragma unroll
  for (int i = 0; i < 2; i++)
#pragma unroll
    for (int j = 0; j < 2; j++)
#pragma unroll
      for (int r = 0; r < 16; r++) acc[i][j][r] = 0.f;

  const int niter = K >> 6;
  // prologue: tile 0 into buf 0
  if constexpr (CVTA) {
    LOAD_A4(0);
#pragma unroll
    for (int p = 0; p < 4; p++)
      async16(Bg + (size_t)(p * 64) * ldb, Bs[0] + p * 4096 + tid * 8);
    __builtin_amdgcn_s_waitcnt(0x0F74);    // vmcnt(4): A regs ready, B0 in flight
    CVT_WRITE(As[0], 0);
  } else {
    u16* Ad = As[0]; u16* Bd = Bs[0];
    async16(Ag, Ad + tid * 8);
    async16(Ag + (size_t)64 * lda, Ad + 4096 + tid * 8);
#pragma unroll
    for (int p = 0; p < 4; p++)
      async16(Bg + (size_t)(p * 64) * ldb, Bd + p * 4096 + tid * 8);
  }

  for (int i = 0; i < niter; i++) {
    const int k1 = (i + 1) << 6;
    if constexpr (CVTA) {
      if (i + 1 < niter) {                 // issue A-regs(i+1) + B(i+1)
        LOAD_A4(k1);
        u16* Bd = Bs[(i + 1) & 1];
#pragma unroll
        for (int p = 0; p < 4; p++)
          async16(Bg + (size_t)(p * 64) * ldb + k1, Bd + p * 4096 + tid * 8);
        __builtin_amdgcn_s_waitcnt(0x007A);  // vmcnt(10)+lgkm(0): B(i)+ds_writes done
      } else {
        __builtin_amdgcn_s_waitcnt(0x0072);  // vmcnt(2)+lgkm(0): drain B(i), keep stores
      }
    } else {
      if (i + 1 < niter) {                 // prefetch tile i+1, stays in flight
        u16* Ad = As[(i + 1) & 1]; u16* Bd = Bs[(i + 1) & 1];
        async16(Ag + k1, Ad + tid * 8);
        async16(Ag + (size_t)64 * lda + k1, Ad + 4096 + tid * 8);
#pragma unroll
        for (int p = 0; p < 4; p++)
          async16(Bg + (size_t)(p * 64) * ldb + k1, Bd + p * 4096 + tid * 8);
        __builtin_amdgcn_s_waitcnt(0x0F76);  // vmcnt(6): drain tile i, keep i+1
      } else {
        __builtin_amdgcn_s_waitcnt(0x0F70);  // vmcnt(0)
      }
    }
    __builtin_amdgcn_s_barrier();            // tile i visible to all waves
    __asm__ volatile("" ::: "memory");
    const u16* Ab = As[i & 1];
    const u16* Bb = Bs[i & 1];
#pragma unroll
    for (int kk = 0; kk < 4; kk++) {
      const int pc = ((kk * 2 + half) ^ (l31 & 7)) * 8;
      const bf16x8 a0 = *(const bf16x8*)(Ab + (wm * 64 + l31) * 64 + pc);
      const bf16x8 a1 = *(const bf16x8*)(Ab + (wm * 64 + 32 + l31) * 64 + pc);
      const bf16x8 b0 = *(const bf16x8*)(Bb + (wn * 64 + l31) * 64 + pc);
      const bf16x8 b1 = *(const bf16x8*)(Bb + (wn * 64 + 32 + l31) * 64 + pc);
      acc[0][0] = __builtin_amdgcn_mfma_f32_32x32x16_bf16(a0, b0, acc[0][0], 0, 0, 0);
      acc[0][1] = __builtin_amdgcn_mfma_f32_32x32x16_bf16(a0, b1, acc[0][1], 0, 0, 0);
      acc[1][0] = __builtin_amdgcn_mfma_f32_32x32x16_bf16(a1, b0, acc[1][0], 0, 0, 0);
      acc[1][1] = __builtin_amdgcn_mfma_f32_32x32x16_bf16(a1, b1, acc[1][1], 0, 0, 0);
    }
    if constexpr (CVTA) {
      if (i + 1 < niter) {
        __builtin_amdgcn_s_waitcnt(0x0F74);  // vmcnt(4): A(i+1) regs + old stores done
        CVT_WRITE(As[(i + 1) & 1], k1);      // ds_write next A-tile + Abf writeout
      }
    }
    __asm__ volatile("" ::: "memory");
    __builtin_amdgcn_s_barrier();            // readers done before next overwrite
  }
#undef LOAD_A4
#undef CVT_WRITE

  // C/D layout: col = wn*64 + nt*32 + l31; row_local = wm*64 + mt*32 + (r&3)+8*(r>>2)+4*half
  const int col0 = wn * 64 + l31;

  if constexpr (EPI == 0) {
#pragma unroll
    for (int mt = 0; mt < 2; mt++)
#pragma unroll
      for (int r = 0; r < 16; r++) {
        const int rl = (r & 3) + 8 * (r >> 2) + 4 * half;
        const long long row = (long long)m0 + wm * 64 + mt * 32 + rl;
        Cb[sC * bz + row * ldc + n0 + col0]      = (u16)f2bf(acc[mt][0][r]);
        Cb[sC * bz + row * ldc + n0 + col0 + 32] = (u16)f2bf(acc[mt][1][r]);
      }
    return;
  }

  // ---- LN epilogue (EPI 2/3): +bias, LN over 256 cols per row, ReLU ----
  __syncthreads();                           // full drain before As reuse as scratch
  const float bia0 = bias[col0], bia1 = bias[col0 + 32];
  float s2[2][16];
#pragma unroll
  for (int mt = 0; mt < 2; mt++)
#pragma unroll
    for (int r = 0; r < 16; r++) {
      acc[mt][0][r] += bia0;
      acc[mt][1][r] += bia1;
      s2[mt][r] = acc[mt][0][r] + acc[mt][1][r];
    }
#pragma unroll
  for (int off = 1; off <= 16; off <<= 1)
#pragma unroll
    for (int mt = 0; mt < 2; mt++)
#pragma unroll
      for (int r = 0; r < 16; r++) s2[mt][r] += __shfl_xor(s2[mt][r], off);

  // scratch in As (floats): rowp[4][128] @0, mu[128] @512, iv[128] @640
  float* sm = (float*)As;
  if (l31 == 0) {
#pragma unroll
    for (int mt = 0; mt < 2; mt++)
#pragma unroll
      for (int r = 0; r < 16; r++) {
        const int rl = (r & 3) + 8 * (r >> 2) + 4 * half;
        sm[wn * 128 + wm * 64 + mt * 32 + rl] = s2[mt][r];
      }
  }
  __syncthreads();
  if (tid < 128)
    sm[512 + tid] = (sm[tid] + sm[128 + tid] + sm[256 + tid] + sm[384 + tid]) * (1.f / 256.f);
  __syncthreads();
  float4 mu4[2][4];
#pragma unroll
  for (int mt = 0; mt < 2; mt++)
#pragma unroll
    for (int g = 0; g < 4; g++)
      mu4[mt][g] = *(const float4*)(sm + 512 + wm * 64 + mt * 32 + g * 8 + 4 * half);

  float q2[2][16];
#pragma unroll
  for (int mt = 0; mt < 2; mt++)
#pragma unroll
    for (int r = 0; r < 16; r++) {
      const float mu = ((const float*)&mu4[mt][r >> 2])[r & 3];
      const float d0 = acc[mt][0][r] - mu, d1 = acc[mt][1][r] - mu;
      q2[mt][r] = d0 * d0 + d1 * d1;
    }
#pragma unroll
  for (int off = 1; off <= 16; off <<= 1)
#pragma unroll
    for (int mt = 0; mt < 2; mt++)
#pragma unroll
      for (int r = 0; r < 16; r++) q2[mt][r] += __shfl_xor(q2[mt][r], off);
  __syncthreads();
  if (l31 == 0) {
#pragma unroll
    for (int mt = 0; mt < 2; mt++)
#pragma unroll
      for (int r = 0; r < 16; r++) {
        const int rl = (r & 3) + 8 * (r >> 2) + 4 * half;
        sm[wn * 128 + wm * 64 + mt * 32 + rl] = q2[mt][r];
      }
  }
  __syncthreads();
  if (tid < 128)
    sm[640 + tid] = rsqrtf(
        (sm[tid] + sm[128 + tid] + sm[256 + tid] + sm[384 + tid]) * (1.f / 256.f) + 1e-5f);
  __syncthreads();
  float4 iv4[2][4];
#pragma unroll
  for (int mt = 0; mt < 2; mt++)
#pragma unroll
    for (int g = 0; g < 4; g++)
      iv4[mt][g] = *(const float4*)(sm + 640 + wm * 64 + mt * 32 + g * 8 + 4 * half);

  const float g0 = gam[col0], g1 = gam[col0 + 32];
  const float e0 = bet[col0], e1 = bet[col0 + 32];
  if constexpr (EPI == 2) {
    float c0 = 0.f, c1 = 0.f;
#pragma unroll
    for (int mt = 0; mt < 2; mt++)
#pragma unroll
      for (int r = 0; r < 16; r++) {
        const float mu = ((const float*)&mu4[mt][r >> 2])[r & 3];
        const float iv = ((const float*)&iv4[mt][r >> 2])[r & 3];
        c0 += fmaxf((acc[mt][0][r] - mu) * iv * g0 + e0, 0.f);
        c1 += fmaxf((acc[mt][1][r] - mu) * iv * g1 + e1, 0.f);
      }
    c0 += __shfl_xor(c0, 32);
    c1 += __shfl_xor(c1, 32);
    if (half == 0) {
      atomicAdd(gcn + bz * 256 + col0, c0);
      atomicAdd(gcn + bz * 256 + col0 + 32, c1);
    }
  } else {
    // ---- EPI 3: H-tile (128x256 bf16) -> LDS, then HWT slice = W2T @ Htile^T ----
    // H1loc in Bs (64 KB): row-major [128][256], byte = row*512 + (col*2 ^ ((row&31)<<4))
    char* H1loc = (char*)Bs;
#pragma unroll
    for (int mt = 0; mt < 2; mt++)
#pragma unroll
      for (int r = 0; r < 16; r++) {
        const float mu = ((const float*)&mu4[mt][r >> 2])[r & 3];
        const float iv = ((const float*)&iv4[mt][r >> 2])[r & 3];
        const int rl = (r & 3) + 8 * (r >> 2) + 4 * half;
        const int row = wm * 64 + mt * 32 + rl;              // 0..127
        const float y0 = fmaxf((acc[mt][0][r] - mu) * iv * g0 + e0, 0.f);
        const float y1 = fmaxf((acc[mt][1][r] - mu) * iv * g1 + e1, 0.f);
        const int xo = (row & 31) << 4;
        *(u16*)(H1loc + row * 512 + ((col0 * 2) ^ xo))        = (u16)f2bf(y0);
        *(u16*)(H1loc + row * 512 + (((col0 + 32) * 2) ^ xo)) = (u16)f2bf(y1);
      }
    __syncthreads();   // H1loc complete; sm (As) reads done -> As reusable

    // mini-GEMM: out[o][m] = sum_k W2T[o][k] * Htile[m][k],  o in 0..255, m in 0..127
    u16* Wc = (u16*)As;                        // 2 x 8192 u16 chunk buffers
    const int orow = (w >> 1) * 64, mcol = (w & 1) * 64;
    const int srw2 = tid >> 2;                 // staging: 4 thr/row, 16B each
    const int cl2 = (tid & 3) ^ (srw2 & 3);    // logical 16B slot (phys = tid&3)

    f32x16 a2[2][2];
#pragma unroll
    for (int i = 0; i < 2; i++)
#pragma unroll
      for (int j = 0; j < 2; j++)
#pragma unroll
        for (int r = 0; r < 16; r++) a2[i][j][r] = 0.f;

#define STAGE_W2(c) do {                                                  \
    u16* _d = Wc + ((c) & 1) * 8192 + tid * 8;                            \
    const u16* _s = W2x + (size_t)srw2 * 256 + (c) * 32 + cl2 * 8;        \
    async16(_s, _d);                                                      \
    async16(_s + 128 * 256, _d + 4096);                                   \
  } while (0)

    STAGE_W2(0);
    STAGE_W2(1);
#pragma unroll
    for (int c = 0; c < 8; c++) {
      if (c < 7) __builtin_amdgcn_s_waitcnt(0x0F72);  // vmcnt(2): chunk c landed
      else       __builtin_amdgcn_s_waitcnt(0x0F70);  // vmcnt(0)
      __builtin_amdgcn_s_barrier();
      __asm__ volatile("" ::: "memory");
      const u16* bufc = Wc + (c & 1) * 8192;
#pragma unroll
      for (int kk = 0; kk < 2; kk++) {
        const int sl = kk * 2 + half;
        const int ao = (sl ^ (l31 & 3)) * 8;
        const bf16x8 a0 = *(const bf16x8*)(bufc + (orow + l31) * 32 + ao);
        const bf16x8 a1 = *(const bf16x8*)(bufc + (orow + 32 + l31) * 32 + ao);
        const int kb = (c * 32 + sl * 8) * 2;            // k byte offset
        const int xo = l31 << 4;
        const bf16x8 b0 = *(const bf16x8*)(H1loc + (mcol + l31) * 512 + (kb ^ xo));
        const bf16x8 b1 = *(const bf16x8*)(H1loc + (mcol + 32 + l31) * 512 + (kb ^ xo));
        a2[0][0] = __builtin_amdgcn_mfma_f32_32x32x16_bf16(a0, b0, a2[0][0], 0, 0, 0);
        a2[0][1] = __builtin_amdgcn_mfma_f32_32x32x16_bf16(a0, b1, a2[0][1], 0, 0, 0);
        a2[1][0] = __builtin_amdgcn_mfma_f32_32x32x16_bf16(a1, b0, a2[1][0], 0, 0, 0);
        a2[1][1] = __builtin_amdgcn_mfma_f32_32x32x16_bf16(a1, b1, a2[1][1], 0, 0, 0);
      }
      __asm__ volatile("" ::: "memory");
      __builtin_amdgcn_s_barrier();            // readers done before re-staging
      if (c + 2 < 8) STAGE_W2(c + 2);
    }
#undef STAGE_W2

    // store HWT slice: rows = W2T rows (0..255), cols = m0 + (0..127)
#pragma unroll
    for (int i = 0; i < 2; i++)
#pragma unroll
      for (int j = 0; j < 2; j++)
#pragma unroll
        for (int r = 0; r < 16; r++) {
          const int rl = (r & 3) + 8 * (r >> 2) + 4 * half;
          const long long rowo = orow + i * 32 + rl;
          const long long colg = m0 + mcol + j * 32 + l31;
          Cb[sC * bz + rowo * ldc + colg] = (u16)f2bf(a2[i][j][r]);
        }
  }
}

// fused readout: fused=[gcn/2048, gv]; pred_y=fused@Ws+bs; pred_arr=fused@Wa+ba
__global__ __launch_bounds__(128) void final_kernel(
    const float* __restrict__ gcn, const float* __restrict__ gv,
    const float* __restrict__ Ws, const float* __restrict__ bs,
    const float* __restrict__ Wa, const float* __restrict__ ba,
    float* __restrict__ out)
{
  const int b = blockIdx.x, t = threadIdx.x;
  __shared__ float fused[274];
  fused[t] = gcn[b * 256 + t] * (1.f / 2048.f);
  fused[128 + t] = gcn[b * 256 + 128 + t] * (1.f / 2048.f);
  if (t < 18) fused[256 + t] = gv[b * 18 + t];
  __syncthreads();
  float acc = ba[t];
  for (int i = 0; i < 274; i++) acc = fmaf(fused[i], Wa[i * 128 + t], acc);
  out[16 + b * 128 + t] = acc;
  if (t < 64) {
    float p = 0.f;
    for (int i = t; i < 274; i += 64) p += fused[i] * Ws[i];
#pragma unroll
    for (int off = 32; off >= 1; off >>= 1) p += __shfl_xor(p, off);
    if (t == 0) out[b] = p + bs[0];
  }
}

extern "C" void kernel_launch(void* const* d_in, const int* in_sizes, int n_in,
                              void* d_out, int out_size, void* d_ws, size_t ws_size,
                              hipStream_t stream)
{
  const float* A   = (const float*)d_in[0];   // (16,2048,2048)
  const float* X   = (const float*)d_in[1];   // (16,2048,64)
  const float* GV  = (const float*)d_in[2];   // (16,18)
  const float* W1  = (const float*)d_in[3];   // (64,256)
  const float* b1  = (const float*)d_in[4];
  const float* g1  = (const float*)d_in[5];
  const float* be1 = (const float*)d_in[6];
  const float* W2  = (const float*)d_in[7];   // (256,256)
  const float* b2  = (const float*)d_in[8];
  const float* g2  = (const float*)d_in[9];
  const float* be2 = (const float*)d_in[10];
  const float* Ws  = (const float*)d_in[11];  // (274,1)
  const float* bs  = (const float*)d_in[12];
  const float* Wa  = (const float*)d_in[13];  // (274,128)
  const float* ba  = (const float*)d_in[14];
  float* out = (float*)d_out;
  (void)in_sizes; (void)n_in; (void)out_size; (void)ws_size;

  char* ws = (char*)d_ws;
  u16*   Abf = (u16*)(ws + 0);             // 134,217,728 B (16,2048,2048) bf16
  u16*   Xbf = (u16*)(ws + 134217728);     //   4,194,304 B (16,2048,64)
  u16*   W1T = (u16*)(ws + 138412032);     //      32,768 B (256,64)
  u16*   W2T = (u16*)(ws + 138444800);     //     131,072 B (256,256)
  u16*   XWT = (u16*)(ws + 138575872);     //  16,777,216 B (16,256,2048) = (X@W1)^T
  u16*   HWT = (u16*)(ws + 155353088);     //  16,777,216 B (16,256,2048) = (H1@W2)^T
  float* GCN = (float*)(ws + 172130304);   //      16,384 B (16,256)

  // small prep: X bf16 convert, W1^T, W2^T, GCN zero (A-convert fused into GEMM1)
  prep<<<512, 256, 0, stream>>>(X, Xbf, W1, W1T, W2, W2T, GCN);

  // XWT = (X@W1)^T:  A-op = W1T (256x64), B-op = Xbf (nodes x 64)
  mm128<0, 0><<<dim3(2, 8, 16), 512, 0, stream>>>(
      W1T, Xbf, 64, 64, 64, 2048, 0LL, 131072LL, 524288LL,
      nullptr, nullptr, nullptr, XWT, nullptr, nullptr, nullptr, nullptr);

  // fused: A fp32 -> bf16 (staged in-kernel, panel written to Abf),
  //        H = relu(LN(A @ (X@W1) + b1)) kept in LDS; HWT = (H@W2)^T stored
  mm128<3, 1><<<dim3(16, 1, 16), 512, 0, stream>>>(
      Abf, XWT, 2048, 2048, 2048, 2048, 4194304LL, 524288LL, 524288LL,
      b1, g1, be1, HWT, nullptr, W2T, A, Abf);

  // GCN[b][c] = sum_nodes relu(LN(A @ (H@W2) + b2))
  mm128<2, 0><<<dim3(16, 1, 16), 512, 0, stream>>>(
      Abf, HWT, 2048, 2048, 2048, 256, 4194304LL, 524288LL, 524288LL,
      b2, g2, be2, nullptr, GCN, nullptr, nullptr, nullptr);

  final_kernel<<<16, 128, 0, stream>>>(GCN, GV, Ws, bs, Wa, ba, out);
}

// Round 7
// 546.430 us; speedup vs baseline: 1.0989x; 1.0397x over previous
//
#include <hip/hip_runtime.h>

typedef unsigned short u16;
typedef __attribute__((ext_vector_type(8))) short bf16x8;
typedef __attribute__((ext_vector_type(16))) float f32x16;
typedef __attribute__((ext_vector_type(4))) float f32x4;

__device__ __forceinline__ unsigned f2bf(float f) {
  unsigned u = __float_as_uint(f);
  return (u + 0x7fffu + ((u >> 16) & 1u)) >> 16;  // RNE fp32 -> bf16 bits
}

// async global->LDS, 16B per lane. LDS dest is wave-uniform base + lane*16.
__device__ __forceinline__ void async16(const u16* g, u16* l) {
  __builtin_amdgcn_global_load_lds(
      (const __attribute__((address_space(1))) void*)g,
      (__attribute__((address_space(3))) void*)l, 16, 0, 0);
}

// ---------------------------------------------------------------------------
// Small prep kernel (A-convert lives in the first A-GEMM):
//   X fp32->bf16 (262,144 x 16B), W1^T (64x256 -> 256x64), W2^T (256x256),
//   GCN zero (4096 floats).
// ---------------------------------------------------------------------------
__global__ __launch_bounds__(256) void prep(
    const float* __restrict__ X, u16* __restrict__ Xbf,
    const float* __restrict__ W1, u16* __restrict__ W1T,
    const float* __restrict__ W2, u16* __restrict__ W2T,
    float* __restrict__ GCN)
{
  const long long gid = (long long)blockIdx.x * 256 + threadIdx.x;
  const long long stride = (long long)gridDim.x * 256;
  for (long long i = gid; i < 262144LL; i += stride) {
    const float4 a = ((const float4*)X)[2 * i];
    const float4 b = ((const float4*)X)[2 * i + 1];
    uint4 r;
    r.x = f2bf(a.x) | (f2bf(a.y) << 16);
    r.y = f2bf(a.z) | (f2bf(a.w) << 16);
    r.z = f2bf(b.x) | (f2bf(b.y) << 16);
    r.w = f2bf(b.z) | (f2bf(b.w) << 16);
    ((uint4*)Xbf)[i] = r;
  }
  for (long long i = gid; i < 16384LL; i += stride) {   // W1T[c][r] = W1[r][c]
    const int c = (int)(i >> 6), r = (int)(i & 63);
    W1T[i] = (u16)f2bf(W1[r * 256 + c]);
  }
  for (long long i = gid; i < 65536LL; i += stride) {   // W2T[c][r] = W2[r][c]
    const int c = (int)(i >> 8), r = (int)(i & 255);
    W2T[i] = (u16)f2bf(W2[r * 256 + c]);
  }
  if (gid < 4096) GCN[gid] = 0.f;
}

// ---------------------------------------------------------------------------
// Pipelined MFMA GEMM: C[bz](M x 256-slice) = A[bz] @ B[bz]^T
//   A: m-major k-contiguous bf16 (lda), B: n-major k-contiguous bf16 (ldb).
//   BM=128, BN=256, BK=64, 512 thr (8 waves, 2Mx4N, each 64m x 64n),
//   mfma_32x32x16. Double-buffered LDS; XOR chunk swizzle (phys = log ^ row&7).
//   XCD batch clustering: fid%8 == XCD; each XCD gets 2 whole batches.
// CVTA=1: A-operand staged from fp32 global with on-the-fly bf16 convert
//   (registers -> ds_write, same physical LDS layout) and the converted
//   panel is streamed out to AbfW for the second A-GEMM. The fp32 loads are
//   NON-TEMPORAL (ext_vector f32x4 -- HIP float4 rejected by the builtin):
//   A fp32 is touched exactly once, and the nt policy keeps the 268 MB stream
//   from evicting the freshly-written Abf (134 MB, L3-fit) so the second
//   A-GEMM re-reads Abf from Infinity Cache instead of HBM.
//   vmcnt ledger: steady {B(i)x4, St(i)x2} + issue {Ax4, Bx4} ->
//   wait vmcnt(10)+lgkm(0) drains B(i); post-MFMA vmcnt(4) frees A-regs/stores;
//   last iter vmcnt(2).
// EPI: 0 = plain bf16 store
//      2 = +bias,LN(256),ReLU -> column sums atomicAdd into gcn
//      3 = +bias,LN(256),ReLU -> keep bf16 tile in LDS, then fused
//          HWT-slice GEMM: out[256x128] = W2T(256x256) @ Htile^T -> Cb
// ---------------------------------------------------------------------------
template<int EPI, int CVTA>
__global__ __launch_bounds__(512, 2) void mm128(
    const u16* __restrict__ Aop, const u16* __restrict__ Bop,
    int K, int lda, int ldb, int ldc,
    long long sA, long long sB, long long sC,
    const float* __restrict__ bias, const float* __restrict__ gam,
    const float* __restrict__ bet, u16* __restrict__ Cb, float* __restrict__ gcn,
    const u16* __restrict__ W2x, const float* __restrict__ Afp,
    u16* __restrict__ AbfW)
{
  __shared__ __align__(16) u16 As[2][128 * 64];   // 2 x 16 KB
  __shared__ __align__(16) u16 Bs[2][256 * 64];   // 2 x 32 KB
  const int tid = threadIdx.x;
  const int w = tid >> 6, lane = tid & 63, l31 = lane & 31, half = lane >> 5;
  const int wm = w >> 2, wn = w & 3;              // wave tile: 64m x 64n

  // XCD batch clustering (grid is always 16 batches, pb blocks per batch)
  const int fid = blockIdx.x + gridDim.x * (blockIdx.y + gridDim.y * blockIdx.z);
  const int pb = gridDim.x * gridDim.y;
  int idx = fid >> 3;
  int bz = fid & 7;
  if (idx >= pb) { bz += 8; idx -= pb; }
  const int m0 = (int)(idx % gridDim.x) * 128;
  const int n0 = (int)(idx / gridDim.x) * 256;

  // staging map: each call covers 64 rows; thread -> (row tid>>3, phys chunk tid&7),
  // logical chunk = phys ^ (row&7)
  const int srow = tid >> 3;
  const int clog = (tid & 7) ^ (srow & 7);
  const u16* Ag = Aop + sA * bz + (size_t)(m0 + srow) * lda + clog * 8;
  const u16* Bg = Bop + sB * bz + (size_t)(n0 + srow) * ldb + clog * 8;

  // CVTA path: linear logical chunk ch8 = tid&7; ds_write to phys = ch8^(row&7)
  const int ch8 = tid & 7;
  const float* Af = CVTA ? (Afp + sA * bz + (size_t)(m0 + srow) * lda + ch8 * 8) : nullptr;
  u16* Aw = CVTA ? (AbfW + sA * bz + (size_t)(m0 + srow) * lda + ch8 * 8) : nullptr;
  const int dsoff = srow * 64 + ((ch8 ^ (srow & 7)) * 8);  // u16 units

  f32x4 a4[4];
#define LOAD_A4(k) do {                                                       \
    a4[0] = __builtin_nontemporal_load((const f32x4*)(Af + (k)));             \
    a4[1] = __builtin_nontemporal_load((const f32x4*)(Af + (k) + 4));         \
    a4[2] = __builtin_nontemporal_load((const f32x4*)(Af + (size_t)64 * lda + (k)));     \
    a4[3] = __builtin_nontemporal_load((const f32x4*)(Af + (size_t)64 * lda + (k) + 4)); \
  } while (0)
#define CVT_WRITE(dst, k) do {                                            \
    uint4 r0, r1;                                                         \
    r0.x = f2bf(a4[0][0]) | (f2bf(a4[0][1]) << 16);                       \
    r0.y = f2bf(a4[0][2]) | (f2bf(a4[0][3]) << 16);                       \
    r0.z = f2bf(a4[1][0]) | (f2bf(a4[1][1]) << 16);                       \
    r0.w = f2bf(a4[1][2]) | (f2bf(a4[1][3]) << 16);                       \
    r1.x = f2bf(a4[2][0]) | (f2bf(a4[2][1]) << 16);                       \
    r1.y = f2bf(a4[2][2]) | (f2bf(a4[2][3]) << 16);                       \
    r1.z = f2bf(a4[3][0]) | (f2bf(a4[3][1]) << 16);                       \
    r1.w = f2bf(a4[3][2]) | (f2bf(a4[3][3]) << 16);                       \
    *(uint4*)((dst) + dsoff)        = r0;                                 \
    *(uint4*)((dst) + 4096 + dsoff) = r1;                                 \
    *(uint4*)(Aw + (k))                      = r0;                        \
    *(uint4*)(Aw + (size_t)64 * lda + (k))   = r1;                        \
  } while (0)

  f32x16 acc[2][2];
#pragma unroll
  for (int i = 0; i < 2; i++)
#pragma unroll
    for (int j = 0; j < 2; j++)
#pragma unroll
      for (int r = 0; r < 16; r++) acc[i][j][r] = 0.f;

  const int niter = K >> 6;
  // prologue: tile 0 into buf 0
  if constexpr (CVTA) {
    LOAD_A4(0);
#pragma unroll
    for (int p = 0; p < 4; p++)
      async16(Bg + (size_t)(p * 64) * ldb, Bs[0] + p * 4096 + tid * 8);
    __builtin_amdgcn_s_waitcnt(0x0F74);    // vmcnt(4): A regs ready, B0 in flight
    CVT_WRITE(As[0], 0);
  } else {
    u16* Ad = As[0]; u16* Bd = Bs[0];
    async16(Ag, Ad + tid * 8);
    async16(Ag + (size_t)64 * lda, Ad + 4096 + tid * 8);
#pragma unroll
    for (int p = 0; p < 4; p++)
      async16(Bg + (size_t)(p * 64) * ldb, Bd + p * 4096 + tid * 8);
  }

  for (int i = 0; i < niter; i++) {
    const int k1 = (i + 1) << 6;
    if constexpr (CVTA) {
      if (i + 1 < niter) {                 // issue A-regs(i+1) + B(i+1)
        LOAD_A4(k1);
        u16* Bd = Bs[(i + 1) & 1];
#pragma unroll
        for (int p = 0; p < 4; p++)
          async16(Bg + (size_t)(p * 64) * ldb + k1, Bd + p * 4096 + tid * 8);
        __builtin_amdgcn_s_waitcnt(0x007A);  // vmcnt(10)+lgkm(0): B(i)+ds_writes done
      } else {
        __builtin_amdgcn_s_waitcnt(0x0072);  // vmcnt(2)+lgkm(0): drain B(i), keep stores
      }
    } else {
      if (i + 1 < niter) {                 // prefetch tile i+1, stays in flight
        u16* Ad = As[(i + 1) & 1]; u16* Bd = Bs[(i + 1) & 1];
        async16(Ag + k1, Ad + tid * 8);
        async16(Ag + (size_t)64 * lda + k1, Ad + 4096 + tid * 8);
#pragma unroll
        for (int p = 0; p < 4; p++)
          async16(Bg + (size_t)(p * 64) * ldb + k1, Bd + p * 4096 + tid * 8);
        __builtin_amdgcn_s_waitcnt(0x0F76);  // vmcnt(6): drain tile i, keep i+1
      } else {
        __builtin_amdgcn_s_waitcnt(0x0F70);  // vmcnt(0)
      }
    }
    __builtin_amdgcn_s_barrier();            // tile i visible to all waves
    __asm__ volatile("" ::: "memory");
    const u16* Ab = As[i & 1];
    const u16* Bb = Bs[i & 1];
#pragma unroll
    for (int kk = 0; kk < 4; kk++) {
      const int pc = ((kk * 2 + half) ^ (l31 & 7)) * 8;
      const bf16x8 a0 = *(const bf16x8*)(Ab + (wm * 64 + l31) * 64 + pc);
      const bf16x8 a1 = *(const bf16x8*)(Ab + (wm * 64 + 32 + l31) * 64 + pc);
      const bf16x8 b0 = *(const bf16x8*)(Bb + (wn * 64 + l31) * 64 + pc);
      const bf16x8 b1 = *(const bf16x8*)(Bb + (wn * 64 + 32 + l31) * 64 + pc);
      acc[0][0] = __builtin_amdgcn_mfma_f32_32x32x16_bf16(a0, b0, acc[0][0], 0, 0, 0);
      acc[0][1] = __builtin_amdgcn_mfma_f32_32x32x16_bf16(a0, b1, acc[0][1], 0, 0, 0);
      acc[1][0] = __builtin_amdgcn_mfma_f32_32x32x16_bf16(a1, b0, acc[1][0], 0, 0, 0);
      acc[1][1] = __builtin_amdgcn_mfma_f32_32x32x16_bf16(a1, b1, acc[1][1], 0, 0, 0);
    }
    if constexpr (CVTA) {
      if (i + 1 < niter) {
        __builtin_amdgcn_s_waitcnt(0x0F74);  // vmcnt(4): A(i+1) regs + old stores done
        CVT_WRITE(As[(i + 1) & 1], k1);      // ds_write next A-tile + Abf writeout
      }
    }
    __asm__ volatile("" ::: "memory");
    __builtin_amdgcn_s_barrier();            // readers done before next overwrite
  }
#undef LOAD_A4
#undef CVT_WRITE

  // C/D layout: col = wn*64 + nt*32 + l31; row_local = wm*64 + mt*32 + (r&3)+8*(r>>2)+4*half
  const int col0 = wn * 64 + l31;

  if constexpr (EPI == 0) {
#pragma unroll
    for (int mt = 0; mt < 2; mt++)
#pragma unroll
      for (int r = 0; r < 16; r++) {
        const int rl = (r & 3) + 8 * (r >> 2) + 4 * half;
        const long long row = (long long)m0 + wm * 64 + mt * 32 + rl;
        Cb[sC * bz + row * ldc + n0 + col0]      = (u16)f2bf(acc[mt][0][r]);
        Cb[sC * bz + row * ldc + n0 + col0 + 32] = (u16)f2bf(acc[mt][1][r]);
      }
    return;
  }

  // ---- LN epilogue (EPI 2/3): +bias, LN over 256 cols per row, ReLU ----
  __syncthreads();                           // full drain before As reuse as scratch
  const float bia0 = bias[col0], bia1 = bias[col0 + 32];
  float s2[2][16];
#pragma unroll
  for (int mt = 0; mt < 2; mt++)
#pragma unroll
    for (int r = 0; r < 16; r++) {
      acc[mt][0][r] += bia0;
      acc[mt][1][r] += bia1;
      s2[mt][r] = acc[mt][0][r] + acc[mt][1][r];
    }
#pragma unroll
  for (int off = 1; off <= 16; off <<= 1)
#pragma unroll
    for (int mt = 0; mt < 2; mt++)
#pragma unroll
      for (int r = 0; r < 16; r++) s2[mt][r] += __shfl_xor(s2[mt][r], off);

  // scratch in As (floats): rowp[4][128] @0, mu[128] @512, iv[128] @640
  float* sm = (float*)As;
  if (l31 == 0) {
#pragma unroll
    for (int mt = 0; mt < 2; mt++)
#pragma unroll
      for (int r = 0; r < 16; r++) {
        const int rl = (r & 3) + 8 * (r >> 2) + 4 * half;
        sm[wn * 128 + wm * 64 + mt * 32 + rl] = s2[mt][r];
      }
  }
  __syncthreads();
  if (tid < 128)
    sm[512 + tid] = (sm[tid] + sm[128 + tid] + sm[256 + tid] + sm[384 + tid]) * (1.f / 256.f);
  __syncthreads();
  float4 mu4[2][4];
#pragma unroll
  for (int mt = 0; mt < 2; mt++)
#pragma unroll
    for (int g = 0; g < 4; g++)
      mu4[mt][g] = *(const float4*)(sm + 512 + wm * 64 + mt * 32 + g * 8 + 4 * half);

  float q2[2][16];
#pragma unroll
  for (int mt = 0; mt < 2; mt++)
#pragma unroll
    for (int r = 0; r < 16; r++) {
      const float mu = ((const float*)&mu4[mt][r >> 2])[r & 3];
      const float d0 = acc[mt][0][r] - mu, d1 = acc[mt][1][r] - mu;
      q2[mt][r] = d0 * d0 + d1 * d1;
    }
#pragma unroll
  for (int off = 1; off <= 16; off <<= 1)
#pragma unroll
    for (int mt = 0; mt < 2; mt++)
#pragma unroll
      for (int r = 0; r < 16; r++) q2[mt][r] += __shfl_xor(q2[mt][r], off);
  __syncthreads();
  if (l31 == 0) {
#pragma unroll
    for (int mt = 0; mt < 2; mt++)
#pragma unroll
      for (int r = 0; r < 16; r++) {
        const int rl = (r & 3) + 8 * (r >> 2) + 4 * half;
        sm[wn * 128 + wm * 64 + mt * 32 + rl] = q2[mt][r];
      }
  }
  __syncthreads();
  if (tid < 128)
    sm[640 + tid] = rsqrtf(
        (sm[tid] + sm[128 + tid] + sm[256 + tid] + sm[384 + tid]) * (1.f / 256.f) + 1e-5f);
  __syncthreads();
  float4 iv4[2][4];
#pragma unroll
  for (int mt = 0; mt < 2; mt++)
#pragma unroll
    for (int g = 0; g < 4; g++)
      iv4[mt][g] = *(const float4*)(sm + 640 + wm * 64 + mt * 32 + g * 8 + 4 * half);

  const float g0 = gam[col0], g1 = gam[col0 + 32];
  const float e0 = bet[col0], e1 = bet[col0 + 32];
  if constexpr (EPI == 2) {
    float c0 = 0.f, c1 = 0.f;
#pragma unroll
    for (int mt = 0; mt < 2; mt++)
#pragma unroll
      for (int r = 0; r < 16; r++) {
        const float mu = ((const float*)&mu4[mt][r >> 2])[r & 3];
        const float iv = ((const float*)&iv4[mt][r >> 2])[r & 3];
        c0 += fmaxf((acc[mt][0][r] - mu) * iv * g0 + e0, 0.f);
        c1 += fmaxf((acc[mt][1][r] - mu) * iv * g1 + e1, 0.f);
      }
    c0 += __shfl_xor(c0, 32);
    c1 += __shfl_xor(c1, 32);
    if (half == 0) {
      atomicAdd(gcn + bz * 256 + col0, c0);
      atomicAdd(gcn + bz * 256 + col0 + 32, c1);
    }
  } else {
    // ---- EPI 3: H-tile (128x256 bf16) -> LDS, then HWT slice = W2T @ Htile^T ----
    // H1loc in Bs (64 KB): row-major [128][256], byte = row*512 + (col*2 ^ ((row&31)<<4))
    char* H1loc = (char*)Bs;
#pragma unroll
    for (int mt = 0; mt < 2; mt++)
#pragma unroll
      for (int r = 0; r < 16; r++) {
        const float mu = ((const float*)&mu4[mt][r >> 2])[r & 3];
        const float iv = ((const float*)&iv4[mt][r >> 2])[r & 3];
        const int rl = (r & 3) + 8 * (r >> 2) + 4 * half;
        const int row = wm * 64 + mt * 32 + rl;              // 0..127
        const float y0 = fmaxf((acc[mt][0][r] - mu) * iv * g0 + e0, 0.f);
        const float y1 = fmaxf((acc[mt][1][r] - mu) * iv * g1 + e1, 0.f);
        const int xo = (row & 31) << 4;
        *(u16*)(H1loc + row * 512 + ((col0 * 2) ^ xo))        = (u16)f2bf(y0);
        *(u16*)(H1loc + row * 512 + (((col0 + 32) * 2) ^ xo)) = (u16)f2bf(y1);
      }
    __syncthreads();   // H1loc complete; sm (As) reads done -> As reusable

    // mini-GEMM: out[o][m] = sum_k W2T[o][k] * Htile[m][k],  o in 0..255, m in 0..127
    u16* Wc = (u16*)As;                        // 2 x 8192 u16 chunk buffers
    const int orow = (w >> 1) * 64, mcol = (w & 1) * 64;
    const int srw2 = tid >> 2;                 // staging: 4 thr/row, 16B each
    const int cl2 = (tid & 3) ^ (srw2 & 3);    // logical 16B slot (phys = tid&3)

    f32x16 a2[2][2];
#pragma unroll
    for (int i = 0; i < 2; i++)
#pragma unroll
      for (int j = 0; j < 2; j++)
#pragma unroll
        for (int r = 0; r < 16; r++) a2[i][j][r] = 0.f;

#define STAGE_W2(c) do {                                                  \
    u16* _d = Wc + ((c) & 1) * 8192 + tid * 8;                            \
    const u16* _s = W2x + (size_t)srw2 * 256 + (c) * 32 + cl2 * 8;        \
    async16(_s, _d);                                                      \
    async16(_s + 128 * 256, _d + 4096);                                   \
  } while (0)

    STAGE_W2(0);
    STAGE_W2(1);
#pragma unroll
    for (int c = 0; c < 8; c++) {
      if (c < 7) __builtin_amdgcn_s_waitcnt(0x0F72);  // vmcnt(2): chunk c landed
      else       __builtin_amdgcn_s_waitcnt(0x0F70);  // vmcnt(0)
      __builtin_amdgcn_s_barrier();
      __asm__ volatile("" ::: "memory");
      const u16* bufc = Wc + (c & 1) * 8192;
#pragma unroll
      for (int kk = 0; kk < 2; kk++) {
        const int sl = kk * 2 + half;
        const int ao = (sl ^ (l31 & 3)) * 8;
        const bf16x8 a0 = *(const bf16x8*)(bufc + (orow + l31) * 32 + ao);
        const bf16x8 a1 = *(const bf16x8*)(bufc + (orow + 32 + l31) * 32 + ao);
        const int kb = (c * 32 + sl * 8) * 2;            // k byte offset
        const int xo = l31 << 4;
        const bf16x8 b0 = *(const bf16x8*)(H1loc + (mcol + l31) * 512 + (kb ^ xo));
        const bf16x8 b1 = *(const bf16x8*)(H1loc + (mcol + 32 + l31) * 512 + (kb ^ xo));
        a2[0][0] = __builtin_amdgcn_mfma_f32_32x32x16_bf16(a0, b0, a2[0][0], 0, 0, 0);
        a2[0][1] = __builtin_amdgcn_mfma_f32_32x32x16_bf16(a0, b1, a2[0][1], 0, 0, 0);
        a2[1][0] = __builtin_amdgcn_mfma_f32_32x32x16_bf16(a1, b0, a2[1][0], 0, 0, 0);
        a2[1][1] = __builtin_amdgcn_mfma_f32_32x32x16_bf16(a1, b1, a2[1][1], 0, 0, 0);
      }
      __asm__ volatile("" ::: "memory");
      __builtin_amdgcn_s_barrier();            // readers done before re-staging
      if (c + 2 < 8) STAGE_W2(c + 2);
    }
#undef STAGE_W2

    // store HWT slice: rows = W2T rows (0..255), cols = m0 + (0..127)
#pragma unroll
    for (int i = 0; i < 2; i++)
#pragma unroll
      for (int j = 0; j < 2; j++)
#pragma unroll
        for (int r = 0; r < 16; r++) {
          const int rl = (r & 3) + 8 * (r >> 2) + 4 * half;
          const long long rowo = orow + i * 32 + rl;
          const long long colg = m0 + mcol + j * 32 + l31;
          Cb[sC * bz + rowo * ldc + colg] = (u16)f2bf(a2[i][j][r]);
        }
  }
}

// fused readout: fused=[gcn/2048, gv]; pred_y=fused@Ws+bs; pred_arr=fused@Wa+ba
__global__ __launch_bounds__(128) void final_kernel(
    const float* __restrict__ gcn, const float* __restrict__ gv,
    const float* __restrict__ Ws, const float* __restrict__ bs,
    const float* __restrict__ Wa, const float* __restrict__ ba,
    float* __restrict__ out)
{
  const int b = blockIdx.x, t = threadIdx.x;
  __shared__ float fused[274];
  fused[t] = gcn[b * 256 + t] * (1.f / 2048.f);
  fused[128 + t] = gcn[b * 256 + 128 + t] * (1.f / 2048.f);
  if (t < 18) fused[256 + t] = gv[b * 18 + t];
  __syncthreads();
  float acc = ba[t];
  for (int i = 0; i < 274; i++) acc = fmaf(fused[i], Wa[i * 128 + t], acc);
  out[16 + b * 128 + t] = acc;
  if (t < 64) {
    float p = 0.f;
    for (int i = t; i < 274; i += 64) p += fused[i] * Ws[i];
#pragma unroll
    for (int off = 32; off >= 1; off >>= 1) p += __shfl_xor(p, off);
    if (t == 0) out[b] = p + bs[0];
  }
}

extern "C" void kernel_launch(void* const* d_in, const int* in_sizes, int n_in,
                              void* d_out, int out_size, void* d_ws, size_t ws_size,
                              hipStream_t stream)
{
  const float* A   = (const float*)d_in[0];   // (16,2048,2048)
  const float* X   = (const float*)d_in[1];   // (16,2048,64)
  const float* GV  = (const float*)d_in[2];   // (16,18)
  const float* W1  = (const float*)d_in[3];   // (64,256)
  const float* b1  = (const float*)d_in[4];
  const float* g1  = (const float*)d_in[5];
  const float* be1 = (const float*)d_in[6];
  const float* W2  = (const float*)d_in[7];   // (256,256)
  const float* b2  = (const float*)d_in[8];
  const float* g2  = (const float*)d_in[9];
  const float* be2 = (const float*)d_in[10];
  const float* Ws  = (const float*)d_in[11];  // (274,1)
  const float* bs  = (const float*)d_in[12];
  const float* Wa  = (const float*)d_in[13];  // (274,128)
  const float* ba  = (const float*)d_in[14];
  float* out = (float*)d_out;
  (void)in_sizes; (void)n_in; (void)out_size; (void)ws_size;

  char* ws = (char*)d_ws;
  u16*   Abf = (u16*)(ws + 0);             // 134,217,728 B (16,2048,2048) bf16
  u16*   Xbf = (u16*)(ws + 134217728);     //   4,194,304 B (16,2048,64)
  u16*   W1T = (u16*)(ws + 138412032);     //      32,768 B (256,64)
  u16*   W2T = (u16*)(ws + 138444800);     //     131,072 B (256,256)
  u16*   XWT = (u16*)(ws + 138575872);     //  16,777,216 B (16,256,2048) = (X@W1)^T
  u16*   HWT = (u16*)(ws + 155353088);     //  16,777,216 B (16,256,2048) = (H1@W2)^T
  float* GCN = (float*)(ws + 172130304);   //      16,384 B (16,256)

  // small prep: X bf16 convert, W1^T, W2^T, GCN zero (A-convert fused into GEMM1)
  prep<<<512, 256, 0, stream>>>(X, Xbf, W1, W1T, W2, W2T, GCN);

  // XWT = (X@W1)^T:  A-op = W1T (256x64), B-op = Xbf (nodes x 64)
  mm128<0, 0><<<dim3(2, 8, 16), 512, 0, stream>>>(
      W1T, Xbf, 64, 64, 64, 2048, 0LL, 131072LL, 524288LL,
      nullptr, nullptr, nullptr, XWT, nullptr, nullptr, nullptr, nullptr);

  // fused: A fp32 -> bf16 (nt-staged in-kernel, panel written to Abf),
  //        H = relu(LN(A @ (X@W1) + b1)) kept in LDS; HWT = (H@W2)^T stored
  mm128<3, 1><<<dim3(16, 1, 16), 512, 0, stream>>>(
      Abf, XWT, 2048, 2048, 2048, 2048, 4194304LL, 524288LL, 524288LL,
      b1, g1, be1, HWT, nullptr, W2T, A, Abf);

  // GCN[b][c] = sum_nodes relu(LN(A @ (H@W2) + b2))
  mm128<2, 0><<<dim3(16, 1, 16), 512, 0, stream>>>(
      Abf, HWT, 2048, 2048, 2048, 256, 4194304LL, 524288LL, 524288LL,
      b2, g2, be2, nullptr, GCN, nullptr, nullptr, nullptr);

  final_kernel<<<16, 128, 0, stream>>>(GCN, GV, Ws, bs, Wa, ba, out);
}